// Round 10
// baseline (484.483 us; speedup 1.0000x reference)
//
#include <hip/hip_runtime.h>
#include <cstdint>
#include <cstddef>

#define D 128

typedef __attribute__((ext_vector_type(8))) short bf16x8;
typedef __attribute__((ext_vector_type(4))) float f32x4;
typedef __attribute__((ext_vector_type(8))) _Float16 f16x8;

__device__ __forceinline__ unsigned short f2bf(float f) {
  unsigned int u = __float_as_uint(f);
  unsigned int r = u + 0x7FFFu + ((u >> 16) & 1u);
  return (unsigned short)(r >> 16);
}
__device__ __forceinline__ float bf2f(unsigned short h) {
  return __uint_as_float((unsigned int)h << 16);
}
__device__ __forceinline__ float fast_tanh(float x) {
  float cx = fminf(fmaxf(x, -15.f), 15.f);
  float e = __expf(2.f * cx);
  return (e - 1.f) * __builtin_amdgcn_rcpf(e + 1.f);
}
union HU { _Float16 f; unsigned short u; };

// ---------------- fused pack (12 weight mats) + degree count ----------------
// slots 0..7: bf16 hi at Wp[m*32768+r], bf16 lo at +16384
// slots 8..11: f16 hi / f16 lo (head stage-2/3 weights)
struct WPtrs { const float* w[12]; };

__global__ __launch_bounds__(256) void packcount_kernel(
    WPtrs P, unsigned short* __restrict__ Wp,
    const int* __restrict__ d0, const int* __restrict__ d1,
    int* __restrict__ cnt, int E, int N, int packBlocks) {
  if ((int)blockIdx.x < packBlocks) {
    int tid = blockIdx.x * 256 + threadIdx.x;  // 0..196607
    int m = tid >> 14;
    int r = tid & 16383;
    int b = r & 7, lane = (r >> 3) & 63, ks = (r >> 9) & 3, jt = r >> 11;
    int k = ks * 32 + ((lane >> 4) << 3) + b;
    int j = jt * 16 + (lane & 15);
    float w = P.w[m][k * 128 + j];
    if (m < 8) {
      unsigned short h = f2bf(w);
      Wp[m * 32768 + r] = h;
      Wp[m * 32768 + 16384 + r] = f2bf(w - bf2f(h));
    } else {
      HU hh, ll;
      hh.f = (_Float16)w;
      ll.f = (_Float16)(w - (float)hh.f);
      Wp[m * 32768 + r] = hh.u;
      Wp[m * 32768 + 16384 + r] = ll.u;
    }
  } else {
    int e = ((int)blockIdx.x - packBlocks) * 256 + threadIdx.x;
    if (e < E) {
      atomicAdd(&cnt[d0[e]], 1);
      atomicAdd(&cnt[N + d1[e]], 1);
    }
  }
}

// ---------------- CSR scan ----------------
__global__ __launch_bounds__(256) void scan_part_kernel(const int* __restrict__ cnt,
                                                        int* __restrict__ off,
                                                        int* __restrict__ bsum, int n2) {
  __shared__ int sh[256];
  int t = threadIdx.x;
  int i0 = blockIdx.x * 512 + 2 * t;
  int a0 = (i0 < n2) ? cnt[i0] : 0;
  int a1 = (i0 + 1 < n2) ? cnt[i0 + 1] : 0;
  int s = a0 + a1;
  sh[t] = s;
  __syncthreads();
  for (int d = 1; d < 256; d <<= 1) {
    int v = (t >= d) ? sh[t - d] : 0;
    __syncthreads();
    sh[t] += v;
    __syncthreads();
  }
  int p = sh[t] - s;
  if (i0 < n2) off[i0] = p;
  if (i0 + 1 < n2) off[i0 + 1] = p + a0;
  if (t == 255) bsum[blockIdx.x] = sh[255];
}

__global__ __launch_bounds__(256) void scan_bsum_kernel(int* __restrict__ bsum, int nb,
                                                        int* __restrict__ off_total) {
  __shared__ int sh[256];
  int t = threadIdx.x;
  int s = (t < nb) ? bsum[t] : 0;
  sh[t] = s;
  __syncthreads();
  for (int d = 1; d < 256; d <<= 1) {
    int v = (t >= d) ? sh[t - d] : 0;
    __syncthreads();
    sh[t] += v;
    __syncthreads();
  }
  if (t < nb) bsum[t] = sh[t] - s;
  if (t == 255) *off_total = sh[255];
}

__global__ __launch_bounds__(256) void scan_add_kernel(int* __restrict__ off,
                                                       const int* __restrict__ bsum,
                                                       int* __restrict__ cnt,
                                                       float* __restrict__ dinv, int n2) {
  int add = bsum[blockIdx.x];
  int base = blockIdx.x * 512;
#pragma unroll
  for (int u = 0; u < 2; u++) {
    int i = base + threadIdx.x + u * 256;
    if (i < n2) {
      off[i] += add;
      dinv[i] = rsqrtf((float)cnt[i] + 1.0f);
      cnt[i] = 0;
    }
  }
}

// ---------------- CSR fill + degree histogram (block-range fused) ----------------
__global__ __launch_bounds__(256) void fillhist_kernel(
    const int* __restrict__ ei0, const int* __restrict__ ei1,
    const int* __restrict__ off, int* __restrict__ cnt,
    int* __restrict__ csr, int* __restrict__ hist,
    int E, int N, int fillBlocks, int histBlocks) {
  if ((int)blockIdx.x < fillBlocks) {
    int e = blockIdx.x * 256 + threadIdx.x;
    if (e < E) {
      int s = ei0[e], d = ei0[E + e];
      int p = atomicAdd(&cnt[d], 1);
      csr[off[d] + p] = s;
      s = ei1[e]; d = ei1[E + e];
      p = atomicAdd(&cnt[N + d], 1);
      csr[off[N + d] + p] = s;
    }
  } else {
    __shared__ int lh[512];
    int t = threadIdx.x;
    lh[t] = 0; lh[t + 256] = 0;
    __syncthreads();
    int stride = histBlocks * 256;
    for (int i = ((int)blockIdx.x - fillBlocks) * 256 + t; i < N; i += stride) {
      int key = (off[i + 1] - off[i]) + (off[N + i + 1] - off[N + i]);
      atomicAdd(&lh[key < 511 ? key : 511], 1);
    }
    __syncthreads();
    if (lh[t]) atomicAdd(&hist[t], lh[t]);
    if (lh[t + 256]) atomicAdd(&hist[t + 256], lh[t + 256]);
  }
}

// exclusive scan of 512-bin hist -> cursor
__global__ __launch_bounds__(512) void binscan_kernel(const int* __restrict__ hist,
                                                      int* __restrict__ cursor) {
  __shared__ int sh[512];
  int t = threadIdx.x;
  int s = hist[t];
  sh[t] = s;
  __syncthreads();
  for (int d = 1; d < 512; d <<= 1) {
    int v = (t >= d) ? sh[t - d] : 0;
    __syncthreads();
    sh[t] += v;
    __syncthreads();
  }
  cursor[t] = sh[t] - s;
}

// ---------------- split helper ----------------
__device__ __forceinline__ void split8(const float vv[8], bf16x8& hh, bf16x8& hl) {
#pragma unroll
  for (int c = 0; c < 8; c++) {
    unsigned short h = f2bf(vv[c]);
    hh[c] = (short)h;
    hl[c] = (short)f2bf(vv[c] - bf2f(h));
  }
}

// ---------------- dual GCN matmul body ----------------
template <int BN>
__device__ __forceinline__ void mm_dual_body(
    int bid, const unsigned short* __restrict__ Wp, const float* __restrict__ Af,
    const float* __restrict__ stats, const float* __restrict__ g0,
    const float* __restrict__ bt0, const float* __restrict__ dinv,
    _Float16* __restrict__ tab0, _Float16* __restrict__ tab1,
    int n, int N, float invn) {
  __shared__ float bnsc[128], bnsh[128];
  if (BN) {
    int t = threadIdx.x;
    if (t < 128) {
      float s = 0.f, q = 0.f;
#pragma unroll
      for (int r = 0; r < 8; r++) { s += stats[r * 128 + t]; q += stats[1024 + r * 128 + t]; }
      float mu = s * invn, var = q * invn - mu * mu;
      float sc = g0[t] * rsqrtf(var + 1e-5f);
      bnsc[t] = sc; bnsh[t] = bt0[t] - mu * sc;
    }
    __syncthreads();
  }
  constexpr int WJT = 4, WIT = 4;
  const int lane = threadIdx.x & 63;
  const int wid = threadIdx.x >> 6;
  const int wj = wid % 4, wi = wid / 4;
  const int jtbase = wj * WJT;
  const int ibase = bid * 64 + wi * WIT * 16;
  const int lrow = lane & 15, lgrp = lane >> 4;

  int node[WIT];
  bool valid[WIT];
#pragma unroll
  for (int it = 0; it < WIT; it++) {
    int i = ibase + it * 16 + lrow;
    valid[it] = (i < n);
    node[it] = valid[it] ? i : (n - 1);
  }

  f32x4 acc[WJT][WIT];
#pragma unroll
  for (int jt = 0; jt < WJT; jt++)
#pragma unroll
    for (int it = 0; it < WIT; it++) acc[jt][it] = (f32x4){0.f, 0.f, 0.f, 0.f};

#pragma unroll
  for (int ks = 0; ks < 4; ks++) {
    float sck[8], shk[8];
    if (BN) {
      int cb = ks * 32 + lgrp * 8;
#pragma unroll
      for (int c = 0; c < 8; c++) { sck[c] = bnsc[cb + c]; shk[c] = bnsh[cb + c]; }
    }
    bf16x8 awh[WJT], awl[WJT];
#pragma unroll
    for (int jt = 0; jt < WJT; jt++) {
      int jg = jtbase + jt;
      const unsigned short* base = Wp + ((jg >= 8) ? 32768 : 0);
      size_t fo = (size_t)(((jg & 7) * 4 + ks) * 64 + lane) * 8;
      awh[jt] = *(const bf16x8*)(base + fo);
      awl[jt] = *(const bf16x8*)(base + fo + 16384);
    }
#pragma unroll
    for (int it = 0; it < WIT; it++) {
      const float* src = Af + (size_t)node[it] * 128 + ks * 32 + lgrp * 8;
      float4 u0 = *(const float4*)src;
      float4 u1 = *(const float4*)(src + 4);
      float vv[8] = {u0.x, u0.y, u0.z, u0.w, u1.x, u1.y, u1.z, u1.w};
      if (BN) {
#pragma unroll
        for (int c = 0; c < 8; c++) vv[c] = fmaxf(vv[c] * sck[c] + shk[c], 0.f);
      }
      bf16x8 bhh, bhl;
      split8(vv, bhh, bhl);
#pragma unroll
      for (int jt = 0; jt < WJT; jt++) {
        acc[jt][it] = __builtin_amdgcn_mfma_f32_16x16x32_bf16(awh[jt], bhh, acc[jt][it], 0, 0, 0);
        acc[jt][it] = __builtin_amdgcn_mfma_f32_16x16x32_bf16(awl[jt], bhh, acc[jt][it], 0, 0, 0);
        acc[jt][it] = __builtin_amdgcn_mfma_f32_16x16x32_bf16(awh[jt], bhl, acc[jt][it], 0, 0, 0);
      }
    }
  }

#pragma unroll
  for (int it = 0; it < WIT; it++) {
    if (!valid[it]) continue;
    float d0v = dinv[node[it]];
    float d1v = dinv[N + node[it]];
#pragma unroll
    for (int jt = 0; jt < WJT; jt++) {
      int jg = jtbase + jt;
      float s = (jg < 8) ? d0v : d1v;
      _Float16 o[4];
#pragma unroll
      for (int c = 0; c < 4; c++) o[c] = (_Float16)(acc[jt][it][c] * s);
      _Float16* base = (jg < 8)
          ? (tab0 + (size_t)node[it] * 128 + jg * 16)
          : (tab1 + (size_t)node[it] * 128 + (jg - 8) * 16);
      *(uint2*)(base + lgrp * 4) = *(uint2*)o;
    }
  }
}

__global__ __launch_bounds__(256) void mm_dual_k(
    const unsigned short* __restrict__ Wp, const float* __restrict__ Af,
    const float* __restrict__ stats, const float* __restrict__ g0,
    const float* __restrict__ bt0, const float* __restrict__ dinv,
    _Float16* __restrict__ tab0, _Float16* __restrict__ tab1,
    int n, int N, float invn) {
  mm_dual_body<1>(blockIdx.x, Wp, Af, stats, g0, bt0, dinv, tab0, tab1, n, N, invn);
}

// fused: order-scatter (tiny) + layer-0 mm_dual (no BN)
__global__ __launch_bounds__(256) void scatmm0_kernel(
    const int* __restrict__ off, int* __restrict__ cursor, int* __restrict__ order,
    int sortBlocks,
    const unsigned short* __restrict__ Wp, const float* __restrict__ x,
    const float* __restrict__ dinv, _Float16* __restrict__ tab0,
    _Float16* __restrict__ tab1, int n, int N) {
  if ((int)blockIdx.x < sortBlocks) {
    int stride = sortBlocks * 256;
    for (int i = (int)blockIdx.x * 256 + threadIdx.x; i < N; i += stride) {
      int key = (off[i + 1] - off[i]) + (off[N + i + 1] - off[N + i]);
      int b = key < 511 ? key : 511;
      int pos = atomicAdd(&cursor[b], 1);
      order[pos] = i;
    }
  } else {
    mm_dual_body<0>(blockIdx.x - sortBlocks, Wp, x, nullptr, nullptr, nullptr,
                    dinv, tab0, tab1, n, N, 0.f);
  }
}

// ---------------- gather (degree-sorted order) + fused BN stats ----------------
__global__ __launch_bounds__(256) void gather_kernel(
    const _Float16* __restrict__ tab0, const _Float16* __restrict__ tab1,
    const float* __restrict__ dinv, const int* __restrict__ off,
    const int* __restrict__ csr, const int* __restrict__ order,
    const float* __restrict__ b0, const float* __restrict__ b1,
    float* __restrict__ outh, float* __restrict__ stats, int n, int N) {
  __shared__ float reds[4][128];
  __shared__ float redq[4][128];
  int t = threadIdx.x;
  int g = t >> 4, l = t & 15;
  int pos = blockIdx.x * 16 + g;
  bool valid = pos < n;
  int nd = valid ? order[pos] : 0;
  const f16x8* t0 = (const f16x8*)tab0;
  const f16x8* t1 = (const f16x8*)tab1;
  float s0[8] = {0,0,0,0,0,0,0,0}, s1[8] = {0,0,0,0,0,0,0,0};
  if (valid) {
    f16x8 v = t0[(size_t)nd * 16 + l];
#pragma unroll
    for (int c = 0; c < 8; c++) s0[c] = (float)v[c];
    v = t1[(size_t)nd * 16 + l];
#pragma unroll
    for (int c = 0; c < 8; c++) s1[c] = (float)v[c];
  }
  int a = valid ? off[nd] : 0, b = valid ? off[nd + 1] : 0;
  int j = a;
  for (; j + 3 < b; j += 4) {
    int i0 = csr[j], i1 = csr[j + 1], i2 = csr[j + 2], i3 = csr[j + 3];
    f16x8 v0 = t0[(size_t)i0 * 16 + l];
    f16x8 v1 = t0[(size_t)i1 * 16 + l];
    f16x8 v2 = t0[(size_t)i2 * 16 + l];
    f16x8 v3 = t0[(size_t)i3 * 16 + l];
#pragma unroll
    for (int c = 0; c < 8; c++)
      s0[c] += ((float)v0[c] + (float)v1[c]) + ((float)v2[c] + (float)v3[c]);
  }
  for (; j < b; j++) {
    f16x8 va = t0[(size_t)csr[j] * 16 + l];
#pragma unroll
    for (int c = 0; c < 8; c++) s0[c] += (float)va[c];
  }
  a = valid ? off[N + nd] : 0; b = valid ? off[N + nd + 1] : 0;
  j = a;
  for (; j + 3 < b; j += 4) {
    int i0 = csr[j], i1 = csr[j + 1], i2 = csr[j + 2], i3 = csr[j + 3];
    f16x8 v0 = t1[(size_t)i0 * 16 + l];
    f16x8 v1 = t1[(size_t)i1 * 16 + l];
    f16x8 v2 = t1[(size_t)i2 * 16 + l];
    f16x8 v3 = t1[(size_t)i3 * 16 + l];
#pragma unroll
    for (int c = 0; c < 8; c++)
      s1[c] += ((float)v0[c] + (float)v1[c]) + ((float)v2[c] + (float)v3[c]);
  }
  for (; j < b; j++) {
    f16x8 va = t1[(size_t)csr[j] * 16 + l];
#pragma unroll
    for (int c = 0; c < 8; c++) s1[c] += (float)va[c];
  }
  float o[8] = {0,0,0,0,0,0,0,0};
  if (valid) {
    float d0 = dinv[nd], d1 = dinv[N + nd];
    const float4* B0 = (const float4*)(b0 + l * 8);
    const float4* B1 = (const float4*)(b1 + l * 8);
    float4 ba0 = B0[0], ba1 = B0[1], bb0 = B1[0], bb1 = B1[1];
    float bs[8] = {ba0.x + bb0.x, ba0.y + bb0.y, ba0.z + bb0.z, ba0.w + bb0.w,
                   ba1.x + bb1.x, ba1.y + bb1.y, ba1.z + bb1.z, ba1.w + bb1.w};
#pragma unroll
    for (int c = 0; c < 8; c++) o[c] = d0 * s0[c] + d1 * s1[c] + bs[c];
    float* dst = outh + (size_t)nd * 128 + l * 8;
    *(float4*)dst = make_float4(o[0], o[1], o[2], o[3]);
    *(float4*)(dst + 4) = make_float4(o[4], o[5], o[6], o[7]);
  }
  float sv[8], q[8];
#pragma unroll
  for (int c = 0; c < 8; c++) { sv[c] = o[c]; q[c] = o[c] * o[c]; }
#pragma unroll
  for (int c = 0; c < 8; c++) {
    sv[c] += __shfl_xor(sv[c], 16); sv[c] += __shfl_xor(sv[c], 32);
    q[c] += __shfl_xor(q[c], 16);  q[c] += __shfl_xor(q[c], 32);
  }
  int lane = t & 63, wid = t >> 6;
  if (lane < 16) {
#pragma unroll
    for (int c = 0; c < 8; c++) { reds[wid][lane * 8 + c] = sv[c]; redq[wid][lane * 8 + c] = q[c]; }
  }
  __syncthreads();
  if (t < 128) {
    float ts = reds[0][t] + reds[1][t] + reds[2][t] + reds[3][t];
    float tq = redq[0][t] + redq[1][t] + redq[2][t] + redq[3][t];
    int cp = blockIdx.x & 7;
    atomicAdd(&stats[cp * 128 + t], ts);
    atomicAdd(&stats[1024 + cp * 128 + t], tq);
  }
}

// ---------------- fully-fused heads: e->t->p per head, f16 LDS tiles ----------------
#define TPH 136
__global__ __launch_bounds__(256) void heads3_kernel(
    const unsigned short* __restrict__ Wp,
    const float* __restrict__ h, const float* __restrict__ stats,
    const float* __restrict__ g2, const float* __restrict__ bt2,
    const float* __restrict__ emb1_b, const float* __restrict__ emb2_b,
    const float* __restrict__ ph1_ba, const float* __restrict__ ph1_bb,
    const float* __restrict__ ph2_ba, const float* __restrict__ ph2_bb,
    float* __restrict__ out, int n, float invn) {
  __shared__ float bnsc[128], bnsh[128];
  __shared__ _Float16 tile[2][64 * TPH];
  __shared__ float l2red[2][4][16][2];
  const int t = threadIdx.x;
  if (t < 128) {
    float s = 0.f, q = 0.f;
#pragma unroll
    for (int r = 0; r < 8; r++) { s += stats[r * 128 + t]; q += stats[1024 + r * 128 + t]; }
    float mu = s * invn, var = q * invn - mu * mu;
    float sc = g2[t] * rsqrtf(var + 1e-5f);
    bnsc[t] = sc; bnsh[t] = bt2[t] - mu * sc;
  }
  __syncthreads();

  const int lane = t & 63, wid = t >> 6;
  const int wj = wid & 1, wh = wid >> 1;
  const int lrow = lane & 15, lgrp = lane >> 4;
  const int jtbase = wj * 4;
  const int base = blockIdx.x * 64;
  const size_t ND = (size_t)n * 128;
  _Float16* myt = &tile[wh][0];

  int node[4];
  bool valid[4];
#pragma unroll
  for (int it = 0; it < 4; it++) {
    int i = base + it * 16 + lrow;
    valid[it] = (i < n);
    node[it] = valid[it] ? i : (n - 1);
  }

  f32x4 acc[4][4];
  const unsigned short* slot;
  const float* bias;

  // stage 1: e = tanh(BN(h) @ W[6+wh] + emb_b)  (bf16 split)
  slot = Wp + (size_t)(6 + wh) * 32768;
  bias = wh ? emb2_b : emb1_b;
#pragma unroll
  for (int jt = 0; jt < 4; jt++) {
    float4 b4 = *(const float4*)(bias + (jtbase + jt) * 16 + lgrp * 4);
#pragma unroll
    for (int it = 0; it < 4; it++) acc[jt][it] = (f32x4){b4.x, b4.y, b4.z, b4.w};
  }
#pragma unroll
  for (int ks = 0; ks < 4; ks++) {
    int cb = ks * 32 + lgrp * 8;
    float sck[8], shk[8];
#pragma unroll
    for (int c = 0; c < 8; c++) { sck[c] = bnsc[cb + c]; shk[c] = bnsh[cb + c]; }
    bf16x8 awh[4], awl[4];
#pragma unroll
    for (int jt = 0; jt < 4; jt++) {
      size_t fo = (size_t)(((jtbase + jt) * 4 + ks) * 64 + lane) * 8;
      awh[jt] = *(const bf16x8*)(slot + fo);
      awl[jt] = *(const bf16x8*)(slot + fo + 16384);
    }
#pragma unroll
    for (int it = 0; it < 4; it++) {
      const float* src = h + (size_t)node[it] * 128 + cb;
      float4 u0 = *(const float4*)src;
      float4 u1 = *(const float4*)(src + 4);
      float vv[8] = {u0.x, u0.y, u0.z, u0.w, u1.x, u1.y, u1.z, u1.w};
#pragma unroll
      for (int c = 0; c < 8; c++) vv[c] = vv[c] * sck[c] + shk[c];
      bf16x8 bhh, bhl;
      split8(vv, bhh, bhl);
#pragma unroll
      for (int jt = 0; jt < 4; jt++) {
        acc[jt][it] = __builtin_amdgcn_mfma_f32_16x16x32_bf16(awh[jt], bhh, acc[jt][it], 0, 0, 0);
        acc[jt][it] = __builtin_amdgcn_mfma_f32_16x16x32_bf16(awl[jt], bhh, acc[jt][it], 0, 0, 0);
        acc[jt][it] = __builtin_amdgcn_mfma_f32_16x16x32_bf16(awh[jt], bhl, acc[jt][it], 0, 0, 0);
      }
    }
  }
#pragma unroll
  for (int jt = 0; jt < 4; jt++)
#pragma unroll
    for (int it = 0; it < 4; it++)
#pragma unroll
      for (int c = 0; c < 4; c++) acc[jt][it][c] = fast_tanh(acc[jt][it][c]);

  float rsv[4];
  if (wh == 1) {
#pragma unroll
    for (int it = 0; it < 4; it++) {
      float rs = 0.f;
#pragma unroll
      for (int jt = 0; jt < 4; jt++)
#pragma unroll
        for (int c = 0; c < 4; c++) rs += acc[jt][it][c] * acc[jt][it][c];
      rs += __shfl_xor(rs, 16);
      rs += __shfl_xor(rs, 32);
      rsv[it] = rs;
      if (lane < 16) l2red[1][it][lane][wj] = rs;
    }
  }
  __syncthreads();
  if (wh == 1) {
#pragma unroll
    for (int it = 0; it < 4; it++) {
      float full = rsv[it] + l2red[1][it][lrow][wj ^ 1];
      float scl = 1.f / fmaxf(sqrtf(full), 1e-12f);
#pragma unroll
      for (int jt = 0; jt < 4; jt++)
#pragma unroll
        for (int c = 0; c < 4; c++) acc[jt][it][c] *= scl;
    }
  }
#pragma unroll
  for (int it = 0; it < 4; it++) {
#pragma unroll
    for (int jt = 0; jt < 4; jt++) {
      if (valid[it])
        *(float4*)(out + (size_t)wh * ND + (size_t)node[it] * 128 + (jtbase + jt) * 16 + lgrp * 4) =
            make_float4(acc[jt][it][0], acc[jt][it][1], acc[jt][it][2], acc[jt][it][3]);
      _Float16 o4[4];
#pragma unroll
      for (int c = 0; c < 4; c++) o4[c] = (_Float16)acc[jt][it][c];
      *(uint2*)(myt + (it * 16 + lrow) * TPH + (jtbase + jt) * 16 + lgrp * 4) = *(uint2*)o4;
    }
  }
  __syncthreads();

  // stage 2: t = relu(e @ W[8+2wh] + ph_ba)  (f16 hi/lo)
  slot = Wp + (size_t)(8 + 2 * wh) * 32768;
  bias = wh ? ph2_ba : ph1_ba;
#pragma unroll
  for (int jt = 0; jt < 4; jt++) {
    float4 b4 = *(const float4*)(bias + (jtbase + jt) * 16 + lgrp * 4);
#pragma unroll
    for (int it = 0; it < 4; it++) acc[jt][it] = (f32x4){b4.x, b4.y, b4.z, b4.w};
  }
#pragma unroll
  for (int ks = 0; ks < 4; ks++) {
    f16x8 awh[4], awl[4];
#pragma unroll
    for (int jt = 0; jt < 4; jt++) {
      size_t fo = (size_t)(((jtbase + jt) * 4 + ks) * 64 + lane) * 8;
      awh[jt] = *(const f16x8*)(slot + fo);
      awl[jt] = *(const f16x8*)(slot + fo + 16384);
    }
#pragma unroll
    for (int it = 0; it < 4; it++) {
      f16x8 bh = *(const f16x8*)(myt + (it * 16 + lrow) * TPH + ks * 32 + lgrp * 8);
#pragma unroll
      for (int jt = 0; jt < 4; jt++) {
        acc[jt][it] = __builtin_amdgcn_mfma_f32_16x16x32_f16(awh[jt], bh, acc[jt][it], 0, 0, 0);
        acc[jt][it] = __builtin_amdgcn_mfma_f32_16x16x32_f16(awl[jt], bh, acc[jt][it], 0, 0, 0);
      }
    }
  }
#pragma unroll
  for (int jt = 0; jt < 4; jt++)
#pragma unroll
    for (int it = 0; it < 4; it++)
#pragma unroll
      for (int c = 0; c < 4; c++) acc[jt][it][c] = fmaxf(acc[jt][it][c], 0.f);
  __syncthreads();
#pragma unroll
  for (int it = 0; it < 4; it++)
#pragma unroll
    for (int jt = 0; jt < 4; jt++) {
      _Float16 o4[4];
#pragma unroll
      for (int c = 0; c < 4; c++) o4[c] = (_Float16)acc[jt][it][c];
      *(uint2*)(myt + (it * 16 + lrow) * TPH + (jtbase + jt) * 16 + lgrp * 4) = *(uint2*)o4;
    }
  __syncthreads();

  // stage 3: p = l2norm(t @ W[9+2wh] + ph_bb)  (f16 hi/lo)
  slot = Wp + (size_t)(9 + 2 * wh) * 32768;
  bias = wh ? ph2_bb : ph1_bb;
#pragma unroll
  for (int jt = 0; jt < 4; jt++) {
    float4 b4 = *(const float4*)(bias + (jtbase + jt) * 16 + lgrp * 4);
#pragma unroll
    for (int it = 0; it < 4; it++) acc[jt][it] = (f32x4){b4.x, b4.y, b4.z, b4.w};
  }
#pragma unroll
  for (int ks = 0; ks < 4; ks++) {
    f16x8 awh[4], awl[4];
#pragma unroll
    for (int jt = 0; jt < 4; jt++) {
      size_t fo = (size_t)(((jtbase + jt) * 4 + ks) * 64 + lane) * 8;
      awh[jt] = *(const f16x8*)(slot + fo);
      awl[jt] = *(const f16x8*)(slot + fo + 16384);
    }
#pragma unroll
    for (int it = 0; it < 4; it++) {
      f16x8 bh = *(const f16x8*)(myt + (it * 16 + lrow) * TPH + ks * 32 + lgrp * 8);
#pragma unroll
      for (int jt = 0; jt < 4; jt++) {
        acc[jt][it] = __builtin_amdgcn_mfma_f32_16x16x32_f16(awh[jt], bh, acc[jt][it], 0, 0, 0);
        acc[jt][it] = __builtin_amdgcn_mfma_f32_16x16x32_f16(awl[jt], bh, acc[jt][it], 0, 0, 0);
      }
    }
  }
#pragma unroll
  for (int it = 0; it < 4; it++) {
    float rs = 0.f;
#pragma unroll
    for (int jt = 0; jt < 4; jt++)
#pragma unroll
      for (int c = 0; c < 4; c++) rs += acc[jt][it][c] * acc[jt][it][c];
    rs += __shfl_xor(rs, 16);
    rs += __shfl_xor(rs, 32);
    rsv[it] = rs;
    if (lane < 16) l2red[wh][it][lane][wj] = rs;
  }
  __syncthreads();
#pragma unroll
  for (int it = 0; it < 4; it++) {
    float full = rsv[it] + l2red[wh][it][lrow][wj ^ 1];
    float scl = 1.f / fmaxf(sqrtf(full), 1e-12f);
    if (!valid[it]) continue;
#pragma unroll
    for (int jt = 0; jt < 4; jt++)
      *(float4*)(out + (size_t)(2 + wh) * ND + (size_t)node[it] * 128 + (jtbase + jt) * 16 + lgrp * 4) =
          make_float4(acc[jt][it][0] * scl, acc[jt][it][1] * scl,
                      acc[jt][it][2] * scl, acc[jt][it][3] * scl);
  }
}

// ---------------- launch ----------------
extern "C" void kernel_launch(void* const* d_in, const int* in_sizes, int n_in,
                              void* d_out, int out_size, void* d_ws, size_t ws_size,
                              hipStream_t stream) {
  const float* x      = (const float*)d_in[0];
  const int*   ei0    = (const int*)d_in[1];
  const int*   ei1    = (const int*)d_in[2];
  const float* W0     = (const float*)d_in[3];
  const float* b0     = (const float*)d_in[4];
  const float* W1     = (const float*)d_in[5];
  const float* b1     = (const float*)d_in[6];
  const float* gamma  = (const float*)d_in[7];
  const float* beta   = (const float*)d_in[8];
  const float* emb1_W = (const float*)d_in[9];
  const float* emb1_b = (const float*)d_in[10];
  const float* emb2_W = (const float*)d_in[11];
  const float* emb2_b = (const float*)d_in[12];
  const float* ph1_Wa = (const float*)d_in[13];
  const float* ph1_ba = (const float*)d_in[14];
  const float* ph1_Wb = (const float*)d_in[15];
  const float* ph1_bb = (const float*)d_in[16];
  const float* ph2_Wa = (const float*)d_in[17];
  const float* ph2_ba = (const float*)d_in[18];
  const float* ph2_Wb = (const float*)d_in[19];
  const float* ph2_bb = (const float*)d_in[20];

  const int N = in_sizes[0] / D;
  const int E = in_sizes[1] / 2;
  const int N2 = 2 * N;
  const size_t ND = (size_t)N * D;
  const float invn = 1.0f / (float)N;
  float* out = (float*)d_out;

  char* p = (char*)d_ws;
  auto carve = [&](size_t bytes) -> void* {
    void* r = (void*)p;
    p += (bytes + 255) & ~(size_t)255;
    return r;
  };
  // zero region: cnt + stats + hist (contiguous)
  int*   cnt   = (int*)carve((size_t)N2 * 4);
  float* stats = (float*)carve((size_t)3 * 2048 * 4);
  int*   hist  = (int*)carve(512 * 4);
  size_t zbytes = (size_t)((char*)(hist + 512) - (char*)cnt);
  int*   cursor = (int*)carve(512 * 4);
  int*   order  = (int*)carve((size_t)N * 4);
  int*   off   = (int*)carve((size_t)(N2 + 1) * 4);
  float* dinv  = (float*)carve((size_t)N2 * 4);
  int*   csr   = (int*)carve((size_t)2 * E * 4);
  int*   bsum  = (int*)carve(256 * 4);
  unsigned short* Wp = (unsigned short*)carve((size_t)12 * 32768 * 2);
  float* hbuf = (float*)carve(4 * ND);
  _Float16* tab0 = (_Float16*)carve(2 * ND);
  _Float16* tab1 = (_Float16*)carve(2 * ND);

  const int TPB = 256;
  const int packBlocks = 768;
  const int gridPC = packBlocks + (E + TPB - 1) / TPB;
  const int fillBlocks = (E + TPB - 1) / TPB;
  const int histBlocks = 32;
  const int sortBlocks = 32;
  const int nbScan = (N2 + 511) / 512;
  const int gridDual = (N + 63) / 64;
  const int gridGath = (N + 15) / 16;
  const int gridH3 = (N + 63) / 64;

  WPtrs P;
  P.w[0] = W0;                     P.w[1] = W1;
  P.w[2] = W0 + (size_t)D * D;     P.w[3] = W1 + (size_t)D * D;
  P.w[4] = W0 + (size_t)2 * D * D; P.w[5] = W1 + (size_t)2 * D * D;
  P.w[6] = emb1_W; P.w[7] = emb2_W;
  P.w[8] = ph1_Wa; P.w[9] = ph1_Wb;
  P.w[10] = ph2_Wa; P.w[11] = ph2_Wb;

  hipMemsetAsync(cnt, 0, zbytes, stream);
  packcount_kernel<<<gridPC, TPB, 0, stream>>>(P, Wp, ei0 + E, ei1 + E, cnt, E, N, packBlocks);
  scan_part_kernel<<<nbScan, TPB, 0, stream>>>(cnt, off, bsum, N2);
  scan_bsum_kernel<<<1, TPB, 0, stream>>>(bsum, nbScan, off + N2);
  scan_add_kernel<<<nbScan, TPB, 0, stream>>>(off, bsum, cnt, dinv, N2);
  fillhist_kernel<<<fillBlocks + histBlocks, TPB, 0, stream>>>(
      ei0, ei1, off, cnt, csr, hist, E, N, fillBlocks, histBlocks);
  binscan_kernel<<<1, 512, 0, stream>>>(hist, cursor);
  // fused order-scatter + layer-0 matmul
  scatmm0_kernel<<<sortBlocks + gridDual, TPB, 0, stream>>>(
      off, cursor, order, sortBlocks, Wp, x, dinv, tab0, tab1, N, N);
  gather_kernel<<<gridGath, TPB, 0, stream>>>(tab0, tab1, dinv, off, csr, order,
                                              b0, b1, hbuf, stats, N, N);
  for (int i = 1; i < 3; i++) {
    mm_dual_k<<<gridDual, TPB, 0, stream>>>(Wp + (size_t)(2 * i) * 32768, hbuf,
                                            stats + (size_t)(i - 1) * 2048,
                                            gamma + (i - 1) * D, beta + (i - 1) * D,
                                            dinv, tab0, tab1, N, N, invn);
    gather_kernel<<<gridGath, TPB, 0, stream>>>(tab0, tab1, dinv, off, csr, order,
                                                b0 + i * D, b1 + i * D, hbuf,
                                                stats + (size_t)i * 2048, N, N);
  }
  heads3_kernel<<<gridH3, TPB, 0, stream>>>(
      Wp, hbuf, stats + (size_t)2 * 2048, gamma + 2 * D, beta + 2 * D,
      emb1_b, emb2_b, ph1_ba, ph1_bb, ph2_ba, ph2_bb, out, N, invn);
}

// Round 11
// 348.541 us; speedup vs baseline: 1.3900x; 1.3900x over previous
//
#include <hip/hip_runtime.h>
#include <cstdint>
#include <cstddef>

#define D 128

typedef __attribute__((ext_vector_type(8))) short bf16x8;
typedef __attribute__((ext_vector_type(4))) float f32x4;
typedef __attribute__((ext_vector_type(8))) _Float16 f16x8;

__device__ __forceinline__ unsigned short f2bf(float f) {
  unsigned int u = __float_as_uint(f);
  unsigned int r = u + 0x7FFFu + ((u >> 16) & 1u);
  return (unsigned short)(r >> 16);
}
__device__ __forceinline__ float bf2f(unsigned short h) {
  return __uint_as_float((unsigned int)h << 16);
}
__device__ __forceinline__ float fast_tanh(float x) {
  float cx = fminf(fmaxf(x, -15.f), 15.f);
  float e = __expf(2.f * cx);
  return (e - 1.f) * __builtin_amdgcn_rcpf(e + 1.f);
}
union HU { _Float16 f; unsigned short u; };

// ---------------- fused pack (12 weight mats) + degree count ----------------
// slots 0..7: bf16 hi at Wp[m*32768+r], bf16 lo at +16384
// slots 8..11: f16 hi / f16 lo (head stage-2/3 weights)
struct WPtrs { const float* w[12]; };

__global__ __launch_bounds__(256) void packcount_kernel(
    WPtrs P, unsigned short* __restrict__ Wp,
    const int* __restrict__ d0, const int* __restrict__ d1,
    int* __restrict__ cnt, int E, int N, int packBlocks) {
  if ((int)blockIdx.x < packBlocks) {
    int tid = blockIdx.x * 256 + threadIdx.x;  // 0..196607
    int m = tid >> 14;
    int r = tid & 16383;
    int b = r & 7, lane = (r >> 3) & 63, ks = (r >> 9) & 3, jt = r >> 11;
    int k = ks * 32 + ((lane >> 4) << 3) + b;
    int j = jt * 16 + (lane & 15);
    float w = P.w[m][k * 128 + j];
    if (m < 8) {
      unsigned short h = f2bf(w);
      Wp[m * 32768 + r] = h;
      Wp[m * 32768 + 16384 + r] = f2bf(w - bf2f(h));
    } else {
      HU hh, ll;
      hh.f = (_Float16)w;
      ll.f = (_Float16)(w - (float)hh.f);
      Wp[m * 32768 + r] = hh.u;
      Wp[m * 32768 + 16384 + r] = ll.u;
    }
  } else {
    int e = ((int)blockIdx.x - packBlocks) * 256 + threadIdx.x;
    if (e < E) {
      atomicAdd(&cnt[d0[e]], 1);
      atomicAdd(&cnt[N + d1[e]], 1);
    }
  }
}

// ---------------- CSR scan ----------------
__global__ __launch_bounds__(256) void scan_part_kernel(const int* __restrict__ cnt,
                                                        int* __restrict__ off,
                                                        int* __restrict__ bsum, int n2) {
  __shared__ int sh[256];
  int t = threadIdx.x;
  int i0 = blockIdx.x * 512 + 2 * t;
  int a0 = (i0 < n2) ? cnt[i0] : 0;
  int a1 = (i0 + 1 < n2) ? cnt[i0 + 1] : 0;
  int s = a0 + a1;
  sh[t] = s;
  __syncthreads();
  for (int d = 1; d < 256; d <<= 1) {
    int v = (t >= d) ? sh[t - d] : 0;
    __syncthreads();
    sh[t] += v;
    __syncthreads();
  }
  int p = sh[t] - s;
  if (i0 < n2) off[i0] = p;
  if (i0 + 1 < n2) off[i0 + 1] = p + a0;
  if (t == 255) bsum[blockIdx.x] = sh[255];
}

__global__ __launch_bounds__(256) void scan_bsum_kernel(int* __restrict__ bsum, int nb,
                                                        int* __restrict__ off_total) {
  __shared__ int sh[256];
  int t = threadIdx.x;
  int s = (t < nb) ? bsum[t] : 0;
  sh[t] = s;
  __syncthreads();
  for (int d = 1; d < 256; d <<= 1) {
    int v = (t >= d) ? sh[t - d] : 0;
    __syncthreads();
    sh[t] += v;
    __syncthreads();
  }
  if (t < nb) bsum[t] = sh[t] - s;
  if (t == 255) *off_total = sh[255];
}

__global__ __launch_bounds__(256) void scan_add_kernel(int* __restrict__ off,
                                                       const int* __restrict__ bsum,
                                                       int* __restrict__ cnt,
                                                       float* __restrict__ dinv, int n2) {
  int add = bsum[blockIdx.x];
  int base = blockIdx.x * 512;
#pragma unroll
  for (int u = 0; u < 2; u++) {
    int i = base + threadIdx.x + u * 256;
    if (i < n2) {
      off[i] += add;
      dinv[i] = rsqrtf((float)cnt[i] + 1.0f);
      cnt[i] = 0;
    }
  }
}

__global__ void fill_kernel(const int* __restrict__ ei0, const int* __restrict__ ei1,
                            const int* __restrict__ off, int* __restrict__ cnt,
                            int* __restrict__ csr, int E, int N) {
  int e = blockIdx.x * blockDim.x + threadIdx.x;
  if (e < E) {
    int s = ei0[e], d = ei0[E + e];
    int p = atomicAdd(&cnt[d], 1);
    csr[off[d] + p] = s;
    s = ei1[e]; d = ei1[E + e];
    p = atomicAdd(&cnt[N + d], 1);
    csr[off[N + d] + p] = s;
  }
}

// ---------------- split helper ----------------
__device__ __forceinline__ void split8(const float vv[8], bf16x8& hh, bf16x8& hl) {
#pragma unroll
  for (int c = 0; c < 8; c++) {
    unsigned short h = f2bf(vv[c]);
    hh[c] = (short)h;
    hl[c] = (short)f2bf(vv[c] - bf2f(h));
  }
}

// ---------------- dual GCN matmul (operand-swapped, split precision) ----------------
template <int BN>
__global__ __launch_bounds__(256) void mm_dual(
    const unsigned short* __restrict__ Wp, const float* __restrict__ Af,
    const float* __restrict__ stats, const float* __restrict__ g0,
    const float* __restrict__ bt0, const float* __restrict__ dinv,
    _Float16* __restrict__ tab0, _Float16* __restrict__ tab1,
    int n, int N, float invn) {
  __shared__ float bnsc[128], bnsh[128];
  if (BN) {
    int t = threadIdx.x;
    if (t < 128) {
      float s = 0.f, q = 0.f;
#pragma unroll
      for (int r = 0; r < 8; r++) { s += stats[r * 128 + t]; q += stats[1024 + r * 128 + t]; }
      float mu = s * invn, var = q * invn - mu * mu;
      float sc = g0[t] * rsqrtf(var + 1e-5f);
      bnsc[t] = sc; bnsh[t] = bt0[t] - mu * sc;
    }
    __syncthreads();
  }
  constexpr int WJT = 4, WIT = 4;
  const int lane = threadIdx.x & 63;
  const int wid = threadIdx.x >> 6;
  const int wj = wid % 4, wi = wid / 4;
  const int jtbase = wj * WJT;
  const int ibase = blockIdx.x * 64 + wi * WIT * 16;
  const int lrow = lane & 15, lgrp = lane >> 4;

  int node[WIT];
  bool valid[WIT];
#pragma unroll
  for (int it = 0; it < WIT; it++) {
    int i = ibase + it * 16 + lrow;
    valid[it] = (i < n);
    node[it] = valid[it] ? i : (n - 1);
  }

  f32x4 acc[WJT][WIT];
#pragma unroll
  for (int jt = 0; jt < WJT; jt++)
#pragma unroll
    for (int it = 0; it < WIT; it++) acc[jt][it] = (f32x4){0.f, 0.f, 0.f, 0.f};

#pragma unroll
  for (int ks = 0; ks < 4; ks++) {
    float sck[8], shk[8];
    if (BN) {
      int cb = ks * 32 + lgrp * 8;
#pragma unroll
      for (int c = 0; c < 8; c++) { sck[c] = bnsc[cb + c]; shk[c] = bnsh[cb + c]; }
    }
    bf16x8 awh[WJT], awl[WJT];
#pragma unroll
    for (int jt = 0; jt < WJT; jt++) {
      int jg = jtbase + jt;
      const unsigned short* base = Wp + ((jg >= 8) ? 32768 : 0);
      size_t fo = (size_t)(((jg & 7) * 4 + ks) * 64 + lane) * 8;
      awh[jt] = *(const bf16x8*)(base + fo);
      awl[jt] = *(const bf16x8*)(base + fo + 16384);
    }
#pragma unroll
    for (int it = 0; it < WIT; it++) {
      const float* src = Af + (size_t)node[it] * 128 + ks * 32 + lgrp * 8;
      float4 u0 = *(const float4*)src;
      float4 u1 = *(const float4*)(src + 4);
      float vv[8] = {u0.x, u0.y, u0.z, u0.w, u1.x, u1.y, u1.z, u1.w};
      if (BN) {
#pragma unroll
        for (int c = 0; c < 8; c++) vv[c] = fmaxf(vv[c] * sck[c] + shk[c], 0.f);
      }
      bf16x8 bhh, bhl;
      split8(vv, bhh, bhl);
#pragma unroll
      for (int jt = 0; jt < WJT; jt++) {
        acc[jt][it] = __builtin_amdgcn_mfma_f32_16x16x32_bf16(awh[jt], bhh, acc[jt][it], 0, 0, 0);
        acc[jt][it] = __builtin_amdgcn_mfma_f32_16x16x32_bf16(awl[jt], bhh, acc[jt][it], 0, 0, 0);
        acc[jt][it] = __builtin_amdgcn_mfma_f32_16x16x32_bf16(awh[jt], bhl, acc[jt][it], 0, 0, 0);
      }
    }
  }

#pragma unroll
  for (int it = 0; it < WIT; it++) {
    if (!valid[it]) continue;
    float d0v = dinv[node[it]];
    float d1v = dinv[N + node[it]];
#pragma unroll
    for (int jt = 0; jt < WJT; jt++) {
      int jg = jtbase + jt;
      float s = (jg < 8) ? d0v : d1v;
      _Float16 o[4];
#pragma unroll
      for (int c = 0; c < 4; c++) o[c] = (_Float16)(acc[jt][it][c] * s);
      _Float16* base = (jg < 8)
          ? (tab0 + (size_t)node[it] * 128 + jg * 16)
          : (tab1 + (size_t)node[it] * 128 + (jg - 8) * 16);
      *(uint2*)(base + lgrp * 4) = *(uint2*)o;
    }
  }
}

// ---------------- gather: fused predicated dual-type loop + BN stats ----------------
__global__ __launch_bounds__(256) void gather_kernel(
    const _Float16* __restrict__ tab0, const _Float16* __restrict__ tab1,
    const float* __restrict__ dinv, const int* __restrict__ off,
    const int* __restrict__ csr,
    const float* __restrict__ b0, const float* __restrict__ b1,
    float* __restrict__ outh, float* __restrict__ stats, int n, int N) {
  __shared__ float reds[4][128];
  __shared__ float redq[4][128];
  int t = threadIdx.x;
  int g = t >> 4, l = t & 15;
  int node = blockIdx.x * 16 + g;
  bool valid = node < n;
  int nd = valid ? node : 0;
  const f16x8* t0 = (const f16x8*)tab0;
  const f16x8* t1 = (const f16x8*)tab1;
  float s0[8] = {0,0,0,0,0,0,0,0}, s1[8] = {0,0,0,0,0,0,0,0};
  if (valid) {
    f16x8 v = t0[(size_t)nd * 16 + l];
#pragma unroll
    for (int c = 0; c < 8; c++) s0[c] = (float)v[c];
    v = t1[(size_t)nd * 16 + l];
#pragma unroll
    for (int c = 0; c < 8; c++) s1[c] = (float)v[c];
  }
  int j0 = valid ? off[nd] : 0, e0 = valid ? off[nd + 1] : 0;
  int j1 = valid ? off[N + nd] : 0, e1 = valid ? off[N + nd + 1] : 0;
  while (j0 < e0 || j1 < e1) {
    int idx0[4], idx1[4];
    bool p0[4], p1[4];
#pragma unroll
    for (int k = 0; k < 4; k++) {
      int jj = j0 + k;
      p0[k] = jj < e0;
      idx0[k] = nd;
      if (p0[k]) idx0[k] = csr[jj];
      jj = j1 + k;
      p1[k] = jj < e1;
      idx1[k] = nd;
      if (p1[k]) idx1[k] = csr[jj];
    }
    f16x8 v0[4], v1[4];
#pragma unroll
    for (int k = 0; k < 4; k++) {
      v0[k] = t0[(size_t)idx0[k] * 16 + l];
      v1[k] = t1[(size_t)idx1[k] * 16 + l];
    }
#pragma unroll
    for (int k = 0; k < 4; k++) {
#pragma unroll
      for (int c = 0; c < 8; c++) {
        s0[c] += p0[k] ? (float)v0[k][c] : 0.f;
        s1[c] += p1[k] ? (float)v1[k][c] : 0.f;
      }
    }
    j0 = (j0 + 4 < e0) ? j0 + 4 : e0;
    j1 = (j1 + 4 < e1) ? j1 + 4 : e1;
  }
  float o[8] = {0,0,0,0,0,0,0,0};
  if (valid) {
    float d0 = dinv[nd], d1 = dinv[N + nd];
    const float4* B0 = (const float4*)(b0 + l * 8);
    const float4* B1 = (const float4*)(b1 + l * 8);
    float4 ba0 = B0[0], ba1 = B0[1], bb0 = B1[0], bb1 = B1[1];
    float bs[8] = {ba0.x + bb0.x, ba0.y + bb0.y, ba0.z + bb0.z, ba0.w + bb0.w,
                   ba1.x + bb1.x, ba1.y + bb1.y, ba1.z + bb1.z, ba1.w + bb1.w};
#pragma unroll
    for (int c = 0; c < 8; c++) o[c] = d0 * s0[c] + d1 * s1[c] + bs[c];
    float* dst = outh + (size_t)nd * 128 + l * 8;
    *(float4*)dst = make_float4(o[0], o[1], o[2], o[3]);
    *(float4*)(dst + 4) = make_float4(o[4], o[5], o[6], o[7]);
  }
  float sv[8], q[8];
#pragma unroll
  for (int c = 0; c < 8; c++) { sv[c] = o[c]; q[c] = o[c] * o[c]; }
#pragma unroll
  for (int c = 0; c < 8; c++) {
    sv[c] += __shfl_xor(sv[c], 16); sv[c] += __shfl_xor(sv[c], 32);
    q[c] += __shfl_xor(q[c], 16);  q[c] += __shfl_xor(q[c], 32);
  }
  int lane = t & 63, wid = t >> 6;
  if (lane < 16) {
#pragma unroll
    for (int c = 0; c < 8; c++) { reds[wid][lane * 8 + c] = sv[c]; redq[wid][lane * 8 + c] = q[c]; }
  }
  __syncthreads();
  if (t < 128) {
    float ts = reds[0][t] + reds[1][t] + reds[2][t] + reds[3][t];
    float tq = redq[0][t] + redq[1][t] + redq[2][t] + redq[3][t];
    int cp = blockIdx.x & 7;
    atomicAdd(&stats[cp * 128 + t], ts);
    atomicAdd(&stats[1024 + cp * 128 + t], tq);
  }
}

// ---------------- fully-fused heads: e->t->p per head, f16 LDS tiles ----------------
#define TPH 136
__global__ __launch_bounds__(256) void heads3_kernel(
    const unsigned short* __restrict__ Wp,
    const float* __restrict__ h, const float* __restrict__ stats,
    const float* __restrict__ g2, const float* __restrict__ bt2,
    const float* __restrict__ emb1_b, const float* __restrict__ emb2_b,
    const float* __restrict__ ph1_ba, const float* __restrict__ ph1_bb,
    const float* __restrict__ ph2_ba, const float* __restrict__ ph2_bb,
    float* __restrict__ out, int n, float invn) {
  __shared__ float bnsc[128], bnsh[128];
  __shared__ _Float16 tile[2][64 * TPH];
  __shared__ float l2red[2][4][16][2];
  const int t = threadIdx.x;
  if (t < 128) {
    float s = 0.f, q = 0.f;
#pragma unroll
    for (int r = 0; r < 8; r++) { s += stats[r * 128 + t]; q += stats[1024 + r * 128 + t]; }
    float mu = s * invn, var = q * invn - mu * mu;
    float sc = g2[t] * rsqrtf(var + 1e-5f);
    bnsc[t] = sc; bnsh[t] = bt2[t] - mu * sc;
  }
  __syncthreads();

  const int lane = t & 63, wid = t >> 6;
  const int wj = wid & 1, wh = wid >> 1;
  const int lrow = lane & 15, lgrp = lane >> 4;
  const int jtbase = wj * 4;
  const int base = blockIdx.x * 64;
  const size_t ND = (size_t)n * 128;
  _Float16* myt = &tile[wh][0];

  int node[4];
  bool valid[4];
#pragma unroll
  for (int it = 0; it < 4; it++) {
    int i = base + it * 16 + lrow;
    valid[it] = (i < n);
    node[it] = valid[it] ? i : (n - 1);
  }

  f32x4 acc[4][4];
  const unsigned short* slot;
  const float* bias;

  // stage 1: e = tanh(BN(h) @ W[6+wh] + emb_b)  (bf16 split)
  slot = Wp + (size_t)(6 + wh) * 32768;
  bias = wh ? emb2_b : emb1_b;
#pragma unroll
  for (int jt = 0; jt < 4; jt++) {
    float4 b4 = *(const float4*)(bias + (jtbase + jt) * 16 + lgrp * 4);
#pragma unroll
    for (int it = 0; it < 4; it++) acc[jt][it] = (f32x4){b4.x, b4.y, b4.z, b4.w};
  }
#pragma unroll
  for (int ks = 0; ks < 4; ks++) {
    int cb = ks * 32 + lgrp * 8;
    float sck[8], shk[8];
#pragma unroll
    for (int c = 0; c < 8; c++) { sck[c] = bnsc[cb + c]; shk[c] = bnsh[cb + c]; }
    bf16x8 awh[4], awl[4];
#pragma unroll
    for (int jt = 0; jt < 4; jt++) {
      size_t fo = (size_t)(((jtbase + jt) * 4 + ks) * 64 + lane) * 8;
      awh[jt] = *(const bf16x8*)(slot + fo);
      awl[jt] = *(const bf16x8*)(slot + fo + 16384);
    }
#pragma unroll
    for (int it = 0; it < 4; it++) {
      const float* src = h + (size_t)node[it] * 128 + cb;
      float4 u0 = *(const float4*)src;
      float4 u1 = *(const float4*)(src + 4);
      float vv[8] = {u0.x, u0.y, u0.z, u0.w, u1.x, u1.y, u1.z, u1.w};
#pragma unroll
      for (int c = 0; c < 8; c++) vv[c] = vv[c] * sck[c] + shk[c];
      bf16x8 bhh, bhl;
      split8(vv, bhh, bhl);
#pragma unroll
      for (int jt = 0; jt < 4; jt++) {
        acc[jt][it] = __builtin_amdgcn_mfma_f32_16x16x32_bf16(awh[jt], bhh, acc[jt][it], 0, 0, 0);
        acc[jt][it] = __builtin_amdgcn_mfma_f32_16x16x32_bf16(awl[jt], bhh, acc[jt][it], 0, 0, 0);
        acc[jt][it] = __builtin_amdgcn_mfma_f32_16x16x32_bf16(awh[jt], bhl, acc[jt][it], 0, 0, 0);
      }
    }
  }
#pragma unroll
  for (int jt = 0; jt < 4; jt++)
#pragma unroll
    for (int it = 0; it < 4; it++)
#pragma unroll
      for (int c = 0; c < 4; c++) acc[jt][it][c] = fast_tanh(acc[jt][it][c]);

  float rsv[4];
  if (wh == 1) {
#pragma unroll
    for (int it = 0; it < 4; it++) {
      float rs = 0.f;
#pragma unroll
      for (int jt = 0; jt < 4; jt++)
#pragma unroll
        for (int c = 0; c < 4; c++) rs += acc[jt][it][c] * acc[jt][it][c];
      rs += __shfl_xor(rs, 16);
      rs += __shfl_xor(rs, 32);
      rsv[it] = rs;
      if (lane < 16) l2red[1][it][lane][wj] = rs;
    }
  }
  __syncthreads();
  if (wh == 1) {
#pragma unroll
    for (int it = 0; it < 4; it++) {
      float full = rsv[it] + l2red[1][it][lrow][wj ^ 1];
      float scl = 1.f / fmaxf(sqrtf(full), 1e-12f);
#pragma unroll
      for (int jt = 0; jt < 4; jt++)
#pragma unroll
        for (int c = 0; c < 4; c++) acc[jt][it][c] *= scl;
    }
  }
#pragma unroll
  for (int it = 0; it < 4; it++) {
#pragma unroll
    for (int jt = 0; jt < 4; jt++) {
      if (valid[it])
        *(float4*)(out + (size_t)wh * ND + (size_t)node[it] * 128 + (jtbase + jt) * 16 + lgrp * 4) =
            make_float4(acc[jt][it][0], acc[jt][it][1], acc[jt][it][2], acc[jt][it][3]);
      _Float16 o4[4];
#pragma unroll
      for (int c = 0; c < 4; c++) o4[c] = (_Float16)acc[jt][it][c];
      *(uint2*)(myt + (it * 16 + lrow) * TPH + (jtbase + jt) * 16 + lgrp * 4) = *(uint2*)o4;
    }
  }
  __syncthreads();

  // stage 2: t = relu(e @ W[8+2wh] + ph_ba)  (f16 hi/lo)
  slot = Wp + (size_t)(8 + 2 * wh) * 32768;
  bias = wh ? ph2_ba : ph1_ba;
#pragma unroll
  for (int jt = 0; jt < 4; jt++) {
    float4 b4 = *(const float4*)(bias + (jtbase + jt) * 16 + lgrp * 4);
#pragma unroll
    for (int it = 0; it < 4; it++) acc[jt][it] = (f32x4){b4.x, b4.y, b4.z, b4.w};
  }
#pragma unroll
  for (int ks = 0; ks < 4; ks++) {
    f16x8 awh[4], awl[4];
#pragma unroll
    for (int jt = 0; jt < 4; jt++) {
      size_t fo = (size_t)(((jtbase + jt) * 4 + ks) * 64 + lane) * 8;
      awh[jt] = *(const f16x8*)(slot + fo);
      awl[jt] = *(const f16x8*)(slot + fo + 16384);
    }
#pragma unroll
    for (int it = 0; it < 4; it++) {
      f16x8 bh = *(const f16x8*)(myt + (it * 16 + lrow) * TPH + ks * 32 + lgrp * 8);
#pragma unroll
      for (int jt = 0; jt < 4; jt++) {
        acc[jt][it] = __builtin_amdgcn_mfma_f32_16x16x32_f16(awh[jt], bh, acc[jt][it], 0, 0, 0);
        acc[jt][it] = __builtin_amdgcn_mfma_f32_16x16x32_f16(awl[jt], bh, acc[jt][it], 0, 0, 0);
      }
    }
  }
#pragma unroll
  for (int jt = 0; jt < 4; jt++)
#pragma unroll
    for (int it = 0; it < 4; it++)
#pragma unroll
      for (int c = 0; c < 4; c++) acc[jt][it][c] = fmaxf(acc[jt][it][c], 0.f);
  __syncthreads();
#pragma unroll
  for (int it = 0; it < 4; it++)
#pragma unroll
    for (int jt = 0; jt < 4; jt++) {
      _Float16 o4[4];
#pragma unroll
      for (int c = 0; c < 4; c++) o4[c] = (_Float16)acc[jt][it][c];
      *(uint2*)(myt + (it * 16 + lrow) * TPH + (jtbase + jt) * 16 + lgrp * 4) = *(uint2*)o4;
    }
  __syncthreads();

  // stage 3: p = l2norm(t @ W[9+2wh] + ph_bb)  (f16 hi/lo)
  slot = Wp + (size_t)(9 + 2 * wh) * 32768;
  bias = wh ? ph2_bb : ph1_bb;
#pragma unroll
  for (int jt = 0; jt < 4; jt++) {
    float4 b4 = *(const float4*)(bias + (jtbase + jt) * 16 + lgrp * 4);
#pragma unroll
    for (int it = 0; it < 4; it++) acc[jt][it] = (f32x4){b4.x, b4.y, b4.z, b4.w};
  }
#pragma unroll
  for (int ks = 0; ks < 4; ks++) {
    f16x8 awh[4], awl[4];
#pragma unroll
    for (int jt = 0; jt < 4; jt++) {
      size_t fo = (size_t)(((jtbase + jt) * 4 + ks) * 64 + lane) * 8;
      awh[jt] = *(const f16x8*)(slot + fo);
      awl[jt] = *(const f16x8*)(slot + fo + 16384);
    }
#pragma unroll
    for (int it = 0; it < 4; it++) {
      f16x8 bh = *(const f16x8*)(myt + (it * 16 + lrow) * TPH + ks * 32 + lgrp * 8);
#pragma unroll
      for (int jt = 0; jt < 4; jt++) {
        acc[jt][it] = __builtin_amdgcn_mfma_f32_16x16x32_f16(awh[jt], bh, acc[jt][it], 0, 0, 0);
        acc[jt][it] = __builtin_amdgcn_mfma_f32_16x16x32_f16(awl[jt], bh, acc[jt][it], 0, 0, 0);
      }
    }
  }
#pragma unroll
  for (int it = 0; it < 4; it++) {
    float rs = 0.f;
#pragma unroll
    for (int jt = 0; jt < 4; jt++)
#pragma unroll
      for (int c = 0; c < 4; c++) rs += acc[jt][it][c] * acc[jt][it][c];
    rs += __shfl_xor(rs, 16);
    rs += __shfl_xor(rs, 32);
    rsv[it] = rs;
    if (lane < 16) l2red[wh][it][lane][wj] = rs;
  }
  __syncthreads();
#pragma unroll
  for (int it = 0; it < 4; it++) {
    float full = rsv[it] + l2red[wh][it][lrow][wj ^ 1];
    float scl = 1.f / fmaxf(sqrtf(full), 1e-12f);
    if (!valid[it]) continue;
#pragma unroll
    for (int jt = 0; jt < 4; jt++)
      *(float4*)(out + (size_t)(2 + wh) * ND + (size_t)node[it] * 128 + (jtbase + jt) * 16 + lgrp * 4) =
          make_float4(acc[jt][it][0] * scl, acc[jt][it][1] * scl,
                      acc[jt][it][2] * scl, acc[jt][it][3] * scl);
  }
}

// ---------------- launch ----------------
extern "C" void kernel_launch(void* const* d_in, const int* in_sizes, int n_in,
                              void* d_out, int out_size, void* d_ws, size_t ws_size,
                              hipStream_t stream) {
  const float* x      = (const float*)d_in[0];
  const int*   ei0    = (const int*)d_in[1];
  const int*   ei1    = (const int*)d_in[2];
  const float* W0     = (const float*)d_in[3];
  const float* b0     = (const float*)d_in[4];
  const float* W1     = (const float*)d_in[5];
  const float* b1     = (const float*)d_in[6];
  const float* gamma  = (const float*)d_in[7];
  const float* beta   = (const float*)d_in[8];
  const float* emb1_W = (const float*)d_in[9];
  const float* emb1_b = (const float*)d_in[10];
  const float* emb2_W = (const float*)d_in[11];
  const float* emb2_b = (const float*)d_in[12];
  const float* ph1_Wa = (const float*)d_in[13];
  const float* ph1_ba = (const float*)d_in[14];
  const float* ph1_Wb = (const float*)d_in[15];
  const float* ph1_bb = (const float*)d_in[16];
  const float* ph2_Wa = (const float*)d_in[17];
  const float* ph2_ba = (const float*)d_in[18];
  const float* ph2_Wb = (const float*)d_in[19];
  const float* ph2_bb = (const float*)d_in[20];

  const int N = in_sizes[0] / D;
  const int E = in_sizes[1] / 2;
  const int N2 = 2 * N;
  const size_t ND = (size_t)N * D;
  const float invn = 1.0f / (float)N;
  float* out = (float*)d_out;

  char* p = (char*)d_ws;
  auto carve = [&](size_t bytes) -> void* {
    void* r = (void*)p;
    p += (bytes + 255) & ~(size_t)255;
    return r;
  };
  // zero region: cnt + stats (contiguous, one memset)
  int*   cnt   = (int*)carve((size_t)N2 * 4);
  float* stats = (float*)carve((size_t)3 * 2048 * 4);   // [layer][2][8][128]
  size_t zbytes = (size_t)((char*)(stats + 3 * 2048) - (char*)cnt);
  int*   off   = (int*)carve((size_t)(N2 + 1) * 4);
  float* dinv  = (float*)carve((size_t)N2 * 4);
  int*   csr   = (int*)carve((size_t)2 * E * 4);
  int*   bsum  = (int*)carve(256 * 4);
  unsigned short* Wp = (unsigned short*)carve((size_t)12 * 32768 * 2);
  float* hbuf = (float*)carve(4 * ND);
  _Float16* tab0 = (_Float16*)carve(2 * ND);
  _Float16* tab1 = (_Float16*)carve(2 * ND);

  const int TPB = 256;
  const int packBlocks = 768;
  const int gridPC = packBlocks + (E + TPB - 1) / TPB;
  const int gridE = (E + TPB - 1) / TPB;
  const int nbScan = (N2 + 511) / 512;
  const int gridDual = (N + 63) / 64;
  const int gridGath = (N + 15) / 16;
  const int gridH3 = (N + 63) / 64;

  WPtrs P;
  P.w[0] = W0;                     P.w[1] = W1;
  P.w[2] = W0 + (size_t)D * D;     P.w[3] = W1 + (size_t)D * D;
  P.w[4] = W0 + (size_t)2 * D * D; P.w[5] = W1 + (size_t)2 * D * D;
  P.w[6] = emb1_W; P.w[7] = emb2_W;
  P.w[8] = ph1_Wa; P.w[9] = ph1_Wb;
  P.w[10] = ph2_Wa; P.w[11] = ph2_Wb;

  hipMemsetAsync(cnt, 0, zbytes, stream);
  packcount_kernel<<<gridPC, TPB, 0, stream>>>(P, Wp, ei0 + E, ei1 + E, cnt, E, N, packBlocks);
  scan_part_kernel<<<nbScan, TPB, 0, stream>>>(cnt, off, bsum, N2);
  scan_bsum_kernel<<<1, TPB, 0, stream>>>(bsum, nbScan, off + N2);
  scan_add_kernel<<<nbScan, TPB, 0, stream>>>(off, bsum, cnt, dinv, N2);
  fill_kernel<<<gridE, TPB, 0, stream>>>(ei0, ei1, off, cnt, csr, E, N);

  mm_dual<0><<<gridDual, TPB, 0, stream>>>(Wp, x, nullptr, nullptr, nullptr,
                                           dinv, tab0, tab1, N, N, invn);
  gather_kernel<<<gridGath, TPB, 0, stream>>>(tab0, tab1, dinv, off, csr,
                                              b0, b1, hbuf, stats, N, N);
  for (int i = 1; i < 3; i++) {
    mm_dual<1><<<gridDual, TPB, 0, stream>>>(Wp + (size_t)(2 * i) * 32768, hbuf,
                                             stats + (size_t)(i - 1) * 2048,
                                             gamma + (i - 1) * D, beta + (i - 1) * D,
                                             dinv, tab0, tab1, N, N, invn);
    gather_kernel<<<gridGath, TPB, 0, stream>>>(tab0, tab1, dinv, off, csr,
                                                b0 + i * D, b1 + i * D, hbuf,
                                                stats + (size_t)i * 2048, N, N);
  }
  heads3_kernel<<<gridH3, TPB, 0, stream>>>(
      Wp, hbuf, stats + (size_t)2 * 2048, gamma + 2 * D, beta + 2 * D,
      emb1_b, emb2_b, ph1_ba, ph1_bb, ph2_ba, ph2_bb, out, N, invn);
}

// Round 13
// 310.945 us; speedup vs baseline: 1.5581x; 1.1209x over previous
//
#include <hip/hip_runtime.h>
#include <cstdint>
#include <cstddef>

#define D 128

typedef __attribute__((ext_vector_type(8))) short bf16x8;
typedef __attribute__((ext_vector_type(4))) float f32x4;
typedef __attribute__((ext_vector_type(8))) _Float16 f16x8;
typedef __attribute__((ext_vector_type(4))) unsigned int u32x4;

__device__ __forceinline__ unsigned short f2bf(float f) {
  unsigned int u = __float_as_uint(f);
  unsigned int r = u + 0x7FFFu + ((u >> 16) & 1u);
  return (unsigned short)(r >> 16);
}
__device__ __forceinline__ float bf2f(unsigned short h) {
  return __uint_as_float((unsigned int)h << 16);
}
__device__ __forceinline__ float fast_tanh(float x) {
  float cx = fminf(fmaxf(x, -15.f), 15.f);
  float e = __expf(2.f * cx);
  return (e - 1.f) * __builtin_amdgcn_rcpf(e + 1.f);
}
union HU { _Float16 f; unsigned short u; };

// split 8 fp32 -> bf16 hi + bf16 lo planes via HW packed convert (RNE)
__device__ __forceinline__ void split8(const float vv[8], bf16x8& hh, bf16x8& hl) {
  u32x4 ph, pl;
#pragma unroll
  for (int i = 0; i < 4; i++) {
    unsigned int p;
    asm("v_cvt_pk_bf16_f32 %0, %1, %2" : "=v"(p) : "v"(vv[2 * i]), "v"(vv[2 * i + 1]));
    ph[i] = p;
    float r0 = vv[2 * i] - __uint_as_float(p << 16);
    float r1 = vv[2 * i + 1] - __uint_as_float(p & 0xFFFF0000u);
    unsigned int q;
    asm("v_cvt_pk_bf16_f32 %0, %1, %2" : "=v"(q) : "v"(r0), "v"(r1));
    pl[i] = q;
  }
  hh = __builtin_bit_cast(bf16x8, ph);
  hl = __builtin_bit_cast(bf16x8, pl);
}

// ---------------- fused pack (12 weight mats) + degree count (+edge ranks) ----------------
// slots 0..7: bf16 hi at Wp[m*32768+r], bf16 lo at +16384
// slots 8..11: f16 hi / f16 lo (head stage-2/3 weights)
struct WPtrs { const float* w[12]; };

__global__ __launch_bounds__(256) void packcount_kernel(
    WPtrs P, unsigned short* __restrict__ Wp,
    const int* __restrict__ d0, const int* __restrict__ d1,
    int* __restrict__ cnt, int* __restrict__ rank0, int* __restrict__ rank1,
    int E, int N, int packBlocks) {
  if ((int)blockIdx.x < packBlocks) {
    int tid = blockIdx.x * 256 + threadIdx.x;  // 0..196607
    int m = tid >> 14;
    int r = tid & 16383;
    int b = r & 7, lane = (r >> 3) & 63, ks = (r >> 9) & 3, jt = r >> 11;
    int k = ks * 32 + ((lane >> 4) << 3) + b;
    int j = jt * 16 + (lane & 15);
    float w = P.w[m][k * 128 + j];
    if (m < 8) {
      unsigned short h = f2bf(w);
      Wp[m * 32768 + r] = h;
      Wp[m * 32768 + 16384 + r] = f2bf(w - bf2f(h));
    } else {
      HU hh, ll;
      hh.f = (_Float16)w;
      ll.f = (_Float16)(w - (float)hh.f);
      Wp[m * 32768 + r] = hh.u;
      Wp[m * 32768 + 16384 + r] = ll.u;
    }
  } else {
    int e = ((int)blockIdx.x - packBlocks) * 256 + threadIdx.x;
    if (e < E) {
      rank0[e] = atomicAdd(&cnt[d0[e]], 1);
      rank1[e] = atomicAdd(&cnt[N + d1[e]], 1);
    }
  }
}

// ---------------- CSR scan ----------------
__global__ __launch_bounds__(256) void scan_part_kernel(const int* __restrict__ cnt,
                                                        int* __restrict__ off,
                                                        int* __restrict__ bsum, int n2) {
  __shared__ int sh[256];
  int t = threadIdx.x;
  int i0 = blockIdx.x * 512 + 2 * t;
  int a0 = (i0 < n2) ? cnt[i0] : 0;
  int a1 = (i0 + 1 < n2) ? cnt[i0 + 1] : 0;
  int s = a0 + a1;
  sh[t] = s;
  __syncthreads();
  for (int d = 1; d < 256; d <<= 1) {
    int v = (t >= d) ? sh[t - d] : 0;
    __syncthreads();
    sh[t] += v;
    __syncthreads();
  }
  int p = sh[t] - s;
  if (i0 < n2) off[i0] = p;
  if (i0 + 1 < n2) off[i0 + 1] = p + a0;
  if (t == 255) bsum[blockIdx.x] = sh[255];
}

// merged: every block redundantly scans bsum (nb<=256) in LDS, applies its prefix,
// computes dinv; block 0 writes the grand total off[n2].
__global__ __launch_bounds__(256) void scan_addm_kernel(int* __restrict__ off,
                                                        const int* __restrict__ bsum,
                                                        const int* __restrict__ cnt,
                                                        float* __restrict__ dinv,
                                                        int n2, int nb) {
  __shared__ int sh[256];
  int t = threadIdx.x;
  int s = (t < nb) ? bsum[t] : 0;
  sh[t] = s;
  __syncthreads();
  for (int d = 1; d < 256; d <<= 1) {
    int v = (t >= d) ? sh[t - d] : 0;
    __syncthreads();
    sh[t] += v;
    __syncthreads();
  }
  if (blockIdx.x == 0 && t == 0) off[n2] = sh[nb - 1];  // grand total (fix)
  int add = (blockIdx.x > 0) ? sh[blockIdx.x - 1] : 0;
  int base = blockIdx.x * 512;
#pragma unroll
  for (int u = 0; u < 2; u++) {
    int i = base + t + u * 256;
    if (i < n2) {
      off[i] += add;
      dinv[i] = rsqrtf((float)cnt[i] + 1.0f);
    }
  }
}

// ---------------- dual GCN matmul body ----------------
template <int BN>
__device__ __forceinline__ void mm_dual_body(
    int bid, const unsigned short* __restrict__ Wp, const float* __restrict__ Af,
    const float* __restrict__ stats, const float* __restrict__ g0,
    const float* __restrict__ bt0, const float* __restrict__ dinv,
    _Float16* __restrict__ tab0, _Float16* __restrict__ tab1,
    int n, int N, float invn) {
  __shared__ float bnsc[128], bnsh[128];
  if (BN) {
    int t = threadIdx.x;
    if (t < 128) {
      float s = 0.f, q = 0.f;
#pragma unroll
      for (int r = 0; r < 8; r++) { s += stats[r * 128 + t]; q += stats[1024 + r * 128 + t]; }
      float mu = s * invn, var = q * invn - mu * mu;
      float sc = g0[t] * rsqrtf(var + 1e-5f);
      bnsc[t] = sc; bnsh[t] = bt0[t] - mu * sc;
    }
    __syncthreads();
  }
  constexpr int WJT = 4, WIT = 4;
  const int lane = threadIdx.x & 63;
  const int wid = threadIdx.x >> 6;
  const int wj = wid % 4, wi = wid / 4;
  const int jtbase = wj * WJT;
  const int ibase = bid * 64 + wi * WIT * 16;
  const int lrow = lane & 15, lgrp = lane >> 4;

  int node[WIT];
  bool valid[WIT];
#pragma unroll
  for (int it = 0; it < WIT; it++) {
    int i = ibase + it * 16 + lrow;
    valid[it] = (i < n);
    node[it] = valid[it] ? i : (n - 1);
  }

  f32x4 acc[WJT][WIT];
#pragma unroll
  for (int jt = 0; jt < WJT; jt++)
#pragma unroll
    for (int it = 0; it < WIT; it++) acc[jt][it] = (f32x4){0.f, 0.f, 0.f, 0.f};

#pragma unroll
  for (int ks = 0; ks < 4; ks++) {
    float sck[8], shk[8];
    if (BN) {
      int cb = ks * 32 + lgrp * 8;
#pragma unroll
      for (int c = 0; c < 8; c++) { sck[c] = bnsc[cb + c]; shk[c] = bnsh[cb + c]; }
    }
    bf16x8 awh[WJT], awl[WJT];
#pragma unroll
    for (int jt = 0; jt < WJT; jt++) {
      int jg = jtbase + jt;
      const unsigned short* base = Wp + ((jg >= 8) ? 32768 : 0);
      size_t fo = (size_t)(((jg & 7) * 4 + ks) * 64 + lane) * 8;
      awh[jt] = *(const bf16x8*)(base + fo);
      awl[jt] = *(const bf16x8*)(base + fo + 16384);
    }
#pragma unroll
    for (int it = 0; it < WIT; it++) {
      const float* src = Af + (size_t)node[it] * 128 + ks * 32 + lgrp * 8;
      float4 u0 = *(const float4*)src;
      float4 u1 = *(const float4*)(src + 4);
      float vv[8] = {u0.x, u0.y, u0.z, u0.w, u1.x, u1.y, u1.z, u1.w};
      if (BN) {
#pragma unroll
        for (int c = 0; c < 8; c++) vv[c] = fmaxf(vv[c] * sck[c] + shk[c], 0.f);
      }
      bf16x8 bhh, bhl;
      split8(vv, bhh, bhl);
#pragma unroll
      for (int jt = 0; jt < WJT; jt++) {
        acc[jt][it] = __builtin_amdgcn_mfma_f32_16x16x32_bf16(awh[jt], bhh, acc[jt][it], 0, 0, 0);
        acc[jt][it] = __builtin_amdgcn_mfma_f32_16x16x32_bf16(awl[jt], bhh, acc[jt][it], 0, 0, 0);
        acc[jt][it] = __builtin_amdgcn_mfma_f32_16x16x32_bf16(awh[jt], bhl, acc[jt][it], 0, 0, 0);
      }
    }
  }

#pragma unroll
  for (int it = 0; it < WIT; it++) {
    if (!valid[it]) continue;
    float d0v = dinv[node[it]];
    float d1v = dinv[N + node[it]];
#pragma unroll
    for (int jt = 0; jt < WJT; jt++) {
      int jg = jtbase + jt;
      float s = (jg < 8) ? d0v : d1v;
      _Float16 o[4];
#pragma unroll
      for (int c = 0; c < 4; c++) o[c] = (_Float16)(acc[jt][it][c] * s);
      _Float16* base = (jg < 8)
          ? (tab0 + (size_t)node[it] * 128 + jg * 16)
          : (tab1 + (size_t)node[it] * 128 + (jg - 8) * 16);
      *(uint2*)(base + lgrp * 4) = *(uint2*)o;
    }
  }
}

__global__ __launch_bounds__(256) void mm_dual_k(
    const unsigned short* __restrict__ Wp, const float* __restrict__ Af,
    const float* __restrict__ stats, const float* __restrict__ g0,
    const float* __restrict__ bt0, const float* __restrict__ dinv,
    _Float16* __restrict__ tab0, _Float16* __restrict__ tab1,
    int n, int N, float invn) {
  mm_dual_body<1>(blockIdx.x, Wp, Af, stats, g0, bt0, dinv, tab0, tab1, n, N, invn);
}

// fused: atomic-free CSR fill (blocks [0,fillBlocks)) + layer-0 mm_dual
__global__ __launch_bounds__(256) void fillmm0_kernel(
    const int* __restrict__ ei0, const int* __restrict__ ei1,
    const int* __restrict__ off, const int* __restrict__ rank0,
    const int* __restrict__ rank1, int* __restrict__ csr,
    int E, int fillBlocks,
    const unsigned short* __restrict__ Wp, const float* __restrict__ x,
    const float* __restrict__ dinv, _Float16* __restrict__ tab0,
    _Float16* __restrict__ tab1, int n, int N) {
  if ((int)blockIdx.x < fillBlocks) {
    int e = blockIdx.x * 256 + threadIdx.x;
    if (e < E) {
      int s = ei0[e], d = ei0[E + e];
      csr[off[d] + rank0[e]] = s;
      s = ei1[e]; d = ei1[E + e];
      csr[off[N + d] + rank1[e]] = s;
    }
  } else {
    mm_dual_body<0>(blockIdx.x - fillBlocks, Wp, x, nullptr, nullptr, nullptr,
                    dinv, tab0, tab1, n, N, 0.f);
  }
}

// ---------------- gather + fused BN stats (unroll-4, sequential types) ----------------
__global__ __launch_bounds__(256) void gather_kernel(
    const _Float16* __restrict__ tab0, const _Float16* __restrict__ tab1,
    const float* __restrict__ dinv, const int* __restrict__ off,
    const int* __restrict__ csr,
    const float* __restrict__ b0, const float* __restrict__ b1,
    float* __restrict__ outh, float* __restrict__ stats, int n, int N) {
  __shared__ float reds[4][128];
  __shared__ float redq[4][128];
  int t = threadIdx.x;
  int g = t >> 4, l = t & 15;
  int node = blockIdx.x * 16 + g;
  bool valid = node < n;
  int nd = valid ? node : 0;
  const f16x8* t0 = (const f16x8*)tab0;
  const f16x8* t1 = (const f16x8*)tab1;
  float s0[8] = {0,0,0,0,0,0,0,0}, s1[8] = {0,0,0,0,0,0,0,0};
  if (valid) {
    f16x8 v = t0[(size_t)nd * 16 + l];
#pragma unroll
    for (int c = 0; c < 8; c++) s0[c] = (float)v[c];
    v = t1[(size_t)nd * 16 + l];
#pragma unroll
    for (int c = 0; c < 8; c++) s1[c] = (float)v[c];
  }
  int a = valid ? off[nd] : 0, b = valid ? off[nd + 1] : 0;
  int j = a;
  for (; j + 3 < b; j += 4) {
    int i0 = csr[j], i1 = csr[j + 1], i2 = csr[j + 2], i3 = csr[j + 3];
    f16x8 v0 = t0[(size_t)i0 * 16 + l];
    f16x8 v1 = t0[(size_t)i1 * 16 + l];
    f16x8 v2 = t0[(size_t)i2 * 16 + l];
    f16x8 v3 = t0[(size_t)i3 * 16 + l];
#pragma unroll
    for (int c = 0; c < 8; c++)
      s0[c] += ((float)v0[c] + (float)v1[c]) + ((float)v2[c] + (float)v3[c]);
  }
  for (; j < b; j++) {
    f16x8 va = t0[(size_t)csr[j] * 16 + l];
#pragma unroll
    for (int c = 0; c < 8; c++) s0[c] += (float)va[c];
  }
  a = valid ? off[N + nd] : 0; b = valid ? off[N + nd + 1] : 0;
  j = a;
  for (; j + 3 < b; j += 4) {
    int i0 = csr[j], i1 = csr[j + 1], i2 = csr[j + 2], i3 = csr[j + 3];
    f16x8 v0 = t1[(size_t)i0 * 16 + l];
    f16x8 v1 = t1[(size_t)i1 * 16 + l];
    f16x8 v2 = t1[(size_t)i2 * 16 + l];
    f16x8 v3 = t1[(size_t)i3 * 16 + l];
#pragma unroll
    for (int c = 0; c < 8; c++)
      s1[c] += ((float)v0[c] + (float)v1[c]) + ((float)v2[c] + (float)v3[c]);
  }
  for (; j < b; j++) {
    f16x8 va = t1[(size_t)csr[j] * 16 + l];
#pragma unroll
    for (int c = 0; c < 8; c++) s1[c] += (float)va[c];
  }
  float o[8] = {0,0,0,0,0,0,0,0};
  if (valid) {
    float d0 = dinv[nd], d1 = dinv[N + nd];
    const float4* B0 = (const float4*)(b0 + l * 8);
    const float4* B1 = (const float4*)(b1 + l * 8);
    float4 ba0 = B0[0], ba1 = B0[1], bb0 = B1[0], bb1 = B1[1];
    float bs[8] = {ba0.x + bb0.x, ba0.y + bb0.y, ba0.z + bb0.z, ba0.w + bb0.w,
                   ba1.x + bb1.x, ba1.y + bb1.y, ba1.z + bb1.z, ba1.w + bb1.w};
#pragma unroll
    for (int c = 0; c < 8; c++) o[c] = d0 * s0[c] + d1 * s1[c] + bs[c];
    float* dst = outh + (size_t)nd * 128 + l * 8;
    *(float4*)dst = make_float4(o[0], o[1], o[2], o[3]);
    *(float4*)(dst + 4) = make_float4(o[4], o[5], o[6], o[7]);
  }
  float sv[8], q[8];
#pragma unroll
  for (int c = 0; c < 8; c++) { sv[c] = o[c]; q[c] = o[c] * o[c]; }
#pragma unroll
  for (int c = 0; c < 8; c++) {
    sv[c] += __shfl_xor(sv[c], 16); sv[c] += __shfl_xor(sv[c], 32);
    q[c] += __shfl_xor(q[c], 16);  q[c] += __shfl_xor(q[c], 32);
  }
  int lane = t & 63, wid = t >> 6;
  if (lane < 16) {
#pragma unroll
    for (int c = 0; c < 8; c++) { reds[wid][lane * 8 + c] = sv[c]; redq[wid][lane * 8 + c] = q[c]; }
  }
  __syncthreads();
  if (t < 128) {
    float ts = reds[0][t] + reds[1][t] + reds[2][t] + reds[3][t];
    float tq = redq[0][t] + redq[1][t] + redq[2][t] + redq[3][t];
    int cp = blockIdx.x & 7;
    atomicAdd(&stats[cp * 128 + t], ts);
    atomicAdd(&stats[1024 + cp * 128 + t], tq);
  }
}

// ---------------- fully-fused heads: e->t->p per head, f16 LDS tiles ----------------
#define TPH 136
__global__ __launch_bounds__(256) void heads3_kernel(
    const unsigned short* __restrict__ Wp,
    const float* __restrict__ h, const float* __restrict__ stats,
    const float* __restrict__ g2, const float* __restrict__ bt2,
    const float* __restrict__ emb1_b, const float* __restrict__ emb2_b,
    const float* __restrict__ ph1_ba, const float* __restrict__ ph1_bb,
    const float* __restrict__ ph2_ba, const float* __restrict__ ph2_bb,
    float* __restrict__ out, int n, float invn) {
  __shared__ float bnsc[128], bnsh[128];
  __shared__ _Float16 tile[2][64 * TPH];
  __shared__ float l2red[2][4][16][2];
  const int t = threadIdx.x;
  if (t < 128) {
    float s = 0.f, q = 0.f;
#pragma unroll
    for (int r = 0; r < 8; r++) { s += stats[r * 128 + t]; q += stats[1024 + r * 128 + t]; }
    float mu = s * invn, var = q * invn - mu * mu;
    float sc = g2[t] * rsqrtf(var + 1e-5f);
    bnsc[t] = sc; bnsh[t] = bt2[t] - mu * sc;
  }
  __syncthreads();

  const int lane = t & 63, wid = t >> 6;
  const int wj = wid & 1, wh = wid >> 1;
  const int lrow = lane & 15, lgrp = lane >> 4;
  const int jtbase = wj * 4;
  const int base = blockIdx.x * 64;
  const size_t ND = (size_t)n * 128;
  _Float16* myt = &tile[wh][0];

  int node[4];
  bool valid[4];
#pragma unroll
  for (int it = 0; it < 4; it++) {
    int i = base + it * 16 + lrow;
    valid[it] = (i < n);
    node[it] = valid[it] ? i : (n - 1);
  }

  f32x4 acc[4][4];
  const unsigned short* slot;
  const float* bias;

  // stage 1: e = tanh(BN(h) @ W[6+wh] + emb_b)  (bf16 split)
  slot = Wp + (size_t)(6 + wh) * 32768;
  bias = wh ? emb2_b : emb1_b;
#pragma unroll
  for (int jt = 0; jt < 4; jt++) {
    float4 b4 = *(const float4*)(bias + (jtbase + jt) * 16 + lgrp * 4);
#pragma unroll
    for (int it = 0; it < 4; it++) acc[jt][it] = (f32x4){b4.x, b4.y, b4.z, b4.w};
  }
#pragma unroll
  for (int ks = 0; ks < 4; ks++) {
    int cb = ks * 32 + lgrp * 8;
    float sck[8], shk[8];
#pragma unroll
    for (int c = 0; c < 8; c++) { sck[c] = bnsc[cb + c]; shk[c] = bnsh[cb + c]; }
    bf16x8 awh[4], awl[4];
#pragma unroll
    for (int jt = 0; jt < 4; jt++) {
      size_t fo = (size_t)(((jtbase + jt) * 4 + ks) * 64 + lane) * 8;
      awh[jt] = *(const bf16x8*)(slot + fo);
      awl[jt] = *(const bf16x8*)(slot + fo + 16384);
    }
#pragma unroll
    for (int it = 0; it < 4; it++) {
      const float* src = h + (size_t)node[it] * 128 + cb;
      float4 u0 = *(const float4*)src;
      float4 u1 = *(const float4*)(src + 4);
      float vv[8] = {u0.x, u0.y, u0.z, u0.w, u1.x, u1.y, u1.z, u1.w};
#pragma unroll
      for (int c = 0; c < 8; c++) vv[c] = vv[c] * sck[c] + shk[c];
      bf16x8 bhh, bhl;
      split8(vv, bhh, bhl);
#pragma unroll
      for (int jt = 0; jt < 4; jt++) {
        acc[jt][it] = __builtin_amdgcn_mfma_f32_16x16x32_bf16(awh[jt], bhh, acc[jt][it], 0, 0, 0);
        acc[jt][it] = __builtin_amdgcn_mfma_f32_16x16x32_bf16(awl[jt], bhh, acc[jt][it], 0, 0, 0);
        acc[jt][it] = __builtin_amdgcn_mfma_f32_16x16x32_bf16(awh[jt], bhl, acc[jt][it], 0, 0, 0);
      }
    }
  }
#pragma unroll
  for (int jt = 0; jt < 4; jt++)
#pragma unroll
    for (int it = 0; it < 4; it++)
#pragma unroll
      for (int c = 0; c < 4; c++) acc[jt][it][c] = fast_tanh(acc[jt][it][c]);

  float rsv[4];
  if (wh == 1) {
#pragma unroll
    for (int it = 0; it < 4; it++) {
      float rs = 0.f;
#pragma unroll
      for (int jt = 0; jt < 4; jt++)
#pragma unroll
        for (int c = 0; c < 4; c++) rs += acc[jt][it][c] * acc[jt][it][c];
      rs += __shfl_xor(rs, 16);
      rs += __shfl_xor(rs, 32);
      rsv[it] = rs;
      if (lane < 16) l2red[1][it][lane][wj] = rs;
    }
  }
  __syncthreads();
  if (wh == 1) {
#pragma unroll
    for (int it = 0; it < 4; it++) {
      float full = rsv[it] + l2red[1][it][lrow][wj ^ 1];
      float scl = 1.f / fmaxf(sqrtf(full), 1e-12f);
#pragma unroll
      for (int jt = 0; jt < 4; jt++)
#pragma unroll
        for (int c = 0; c < 4; c++) acc[jt][it][c] *= scl;
    }
  }
#pragma unroll
  for (int it = 0; it < 4; it++) {
#pragma unroll
    for (int jt = 0; jt < 4; jt++) {
      if (valid[it])
        *(float4*)(out + (size_t)wh * ND + (size_t)node[it] * 128 + (jtbase + jt) * 16 + lgrp * 4) =
            make_float4(acc[jt][it][0], acc[jt][it][1], acc[jt][it][2], acc[jt][it][3]);
      _Float16 o4[4];
#pragma unroll
      for (int c = 0; c < 4; c++) o4[c] = (_Float16)acc[jt][it][c];
      *(uint2*)(myt + (it * 16 + lrow) * TPH + (jtbase + jt) * 16 + lgrp * 4) = *(uint2*)o4;
    }
  }
  __syncthreads();

  // stage 2: t = relu(e @ W[8+2wh] + ph_ba)  (f16 hi/lo)
  slot = Wp + (size_t)(8 + 2 * wh) * 32768;
  bias = wh ? ph2_ba : ph1_ba;
#pragma unroll
  for (int jt = 0; jt < 4; jt++) {
    float4 b4 = *(const float4*)(bias + (jtbase + jt) * 16 + lgrp * 4);
#pragma unroll
    for (int it = 0; it < 4; it++) acc[jt][it] = (f32x4){b4.x, b4.y, b4.z, b4.w};
  }
#pragma unroll
  for (int ks = 0; ks < 4; ks++) {
    f16x8 awh[4], awl[4];
#pragma unroll
    for (int jt = 0; jt < 4; jt++) {
      size_t fo = (size_t)(((jtbase + jt) * 4 + ks) * 64 + lane) * 8;
      awh[jt] = *(const f16x8*)(slot + fo);
      awl[jt] = *(const f16x8*)(slot + fo + 16384);
    }
#pragma unroll
    for (int it = 0; it < 4; it++) {
      f16x8 bh = *(const f16x8*)(myt + (it * 16 + lrow) * TPH + ks * 32 + lgrp * 8);
#pragma unroll
      for (int jt = 0; jt < 4; jt++) {
        acc[jt][it] = __builtin_amdgcn_mfma_f32_16x16x32_f16(awh[jt], bh, acc[jt][it], 0, 0, 0);
        acc[jt][it] = __builtin_amdgcn_mfma_f32_16x16x32_f16(awl[jt], bh, acc[jt][it], 0, 0, 0);
      }
    }
  }
#pragma unroll
  for (int jt = 0; jt < 4; jt++)
#pragma unroll
    for (int it = 0; it < 4; it++)
#pragma unroll
      for (int c = 0; c < 4; c++) acc[jt][it][c] = fmaxf(acc[jt][it][c], 0.f);
  __syncthreads();
#pragma unroll
  for (int it = 0; it < 4; it++)
#pragma unroll
    for (int jt = 0; jt < 4; jt++) {
      _Float16 o4[4];
#pragma unroll
      for (int c = 0; c < 4; c++) o4[c] = (_Float16)acc[jt][it][c];
      *(uint2*)(myt + (it * 16 + lrow) * TPH + (jtbase + jt) * 16 + lgrp * 4) = *(uint2*)o4;
    }
  __syncthreads();

  // stage 3: p = l2norm(t @ W[9+2wh] + ph_bb)  (f16 hi/lo)
  slot = Wp + (size_t)(9 + 2 * wh) * 32768;
  bias = wh ? ph2_bb : ph1_bb;
#pragma unroll
  for (int jt = 0; jt < 4; jt++) {
    float4 b4 = *(const float4*)(bias + (jtbase + jt) * 16 + lgrp * 4);
#pragma unroll
    for (int it = 0; it < 4; it++) acc[jt][it] = (f32x4){b4.x, b4.y, b4.z, b4.w};
  }
#pragma unroll
  for (int ks = 0; ks < 4; ks++) {
    f16x8 awh[4], awl[4];
#pragma unroll
    for (int jt = 0; jt < 4; jt++) {
      size_t fo = (size_t)(((jtbase + jt) * 4 + ks) * 64 + lane) * 8;
      awh[jt] = *(const f16x8*)(slot + fo);
      awl[jt] = *(const f16x8*)(slot + fo + 16384);
    }
#pragma unroll
    for (int it = 0; it < 4; it++) {
      f16x8 bh = *(const f16x8*)(myt + (it * 16 + lrow) * TPH + ks * 32 + lgrp * 8);
#pragma unroll
      for (int jt = 0; jt < 4; jt++) {
        acc[jt][it] = __builtin_amdgcn_mfma_f32_16x16x32_f16(awh[jt], bh, acc[jt][it], 0, 0, 0);
        acc[jt][it] = __builtin_amdgcn_mfma_f32_16x16x32_f16(awl[jt], bh, acc[jt][it], 0, 0, 0);
      }
    }
  }
#pragma unroll
  for (int it = 0; it < 4; it++) {
    float rs = 0.f;
#pragma unroll
    for (int jt = 0; jt < 4; jt++)
#pragma unroll
      for (int c = 0; c < 4; c++) rs += acc[jt][it][c] * acc[jt][it][c];
    rs += __shfl_xor(rs, 16);
    rs += __shfl_xor(rs, 32);
    rsv[it] = rs;
    if (lane < 16) l2red[wh][it][lane][wj] = rs;
  }
  __syncthreads();
#pragma unroll
  for (int it = 0; it < 4; it++) {
    float full = rsv[it] + l2red[wh][it][lrow][wj ^ 1];
    float scl = 1.f / fmaxf(sqrtf(full), 1e-12f);
    if (!valid[it]) continue;
#pragma unroll
    for (int jt = 0; jt < 4; jt++)
      *(float4*)(out + (size_t)(2 + wh) * ND + (size_t)node[it] * 128 + (jtbase + jt) * 16 + lgrp * 4) =
          make_float4(acc[jt][it][0] * scl, acc[jt][it][1] * scl,
                      acc[jt][it][2] * scl, acc[jt][it][3] * scl);
  }
}

// ---------------- launch ----------------
extern "C" void kernel_launch(void* const* d_in, const int* in_sizes, int n_in,
                              void* d_out, int out_size, void* d_ws, size_t ws_size,
                              hipStream_t stream) {
  const float* x      = (const float*)d_in[0];
  const int*   ei0    = (const int*)d_in[1];
  const int*   ei1    = (const int*)d_in[2];
  const float* W0     = (const float*)d_in[3];
  const float* b0     = (const float*)d_in[4];
  const float* W1     = (const float*)d_in[5];
  const float* b1     = (const float*)d_in[6];
  const float* gamma  = (const float*)d_in[7];
  const float* beta   = (const float*)d_in[8];
  const float* emb1_W = (const float*)d_in[9];
  const float* emb1_b = (const float*)d_in[10];
  const float* emb2_W = (const float*)d_in[11];
  const float* emb2_b = (const float*)d_in[12];
  const float* ph1_Wa = (const float*)d_in[13];
  const float* ph1_ba = (const float*)d_in[14];
  const float* ph1_Wb = (const float*)d_in[15];
  const float* ph1_bb = (const float*)d_in[16];
  const float* ph2_Wa = (const float*)d_in[17];
  const float* ph2_ba = (const float*)d_in[18];
  const float* ph2_Wb = (const float*)d_in[19];
  const float* ph2_bb = (const float*)d_in[20];

  const int N = in_sizes[0] / D;
  const int E = in_sizes[1] / 2;
  const int N2 = 2 * N;
  const size_t ND = (size_t)N * D;
  const float invn = 1.0f / (float)N;
  float* out = (float*)d_out;

  char* p = (char*)d_ws;
  auto carve = [&](size_t bytes) -> void* {
    void* r = (void*)p;
    p += (bytes + 255) & ~(size_t)255;
    return r;
  };
  // zero region: cnt + stats (contiguous, one memset)
  int*   cnt   = (int*)carve((size_t)N2 * 4);
  float* stats = (float*)carve((size_t)3 * 2048 * 4);   // [layer][2][8][128]
  size_t zbytes = (size_t)((char*)(stats + 3 * 2048) - (char*)cnt);
  int*   off   = (int*)carve((size_t)(N2 + 1) * 4);
  float* dinv  = (float*)carve((size_t)N2 * 4);
  int*   csr   = (int*)carve((size_t)2 * E * 4);
  int*   rank0 = (int*)carve((size_t)E * 4);
  int*   rank1 = (int*)carve((size_t)E * 4);
  int*   bsum  = (int*)carve(256 * 4);
  unsigned short* Wp = (unsigned short*)carve((size_t)12 * 32768 * 2);
  float* hbuf = (float*)carve(4 * ND);
  _Float16* tab0 = (_Float16*)carve(2 * ND);
  _Float16* tab1 = (_Float16*)carve(2 * ND);

  const int TPB = 256;
  const int packBlocks = 768;
  const int gridPC = packBlocks + (E + TPB - 1) / TPB;
  const int fillBlocks = (E + TPB - 1) / TPB;
  const int nbScan = (N2 + 511) / 512;
  const int gridDual = (N + 63) / 64;
  const int gridGath = (N + 15) / 16;
  const int gridH3 = (N + 63) / 64;

  WPtrs P;
  P.w[0] = W0;                     P.w[1] = W1;
  P.w[2] = W0 + (size_t)D * D;     P.w[3] = W1 + (size_t)D * D;
  P.w[4] = W0 + (size_t)2 * D * D; P.w[5] = W1 + (size_t)2 * D * D;
  P.w[6] = emb1_W; P.w[7] = emb2_W;
  P.w[8] = ph1_Wa; P.w[9] = ph1_Wb;
  P.w[10] = ph2_Wa; P.w[11] = ph2_Wb;

  hipMemsetAsync(cnt, 0, zbytes, stream);
  packcount_kernel<<<gridPC, TPB, 0, stream>>>(P, Wp, ei0 + E, ei1 + E, cnt,
                                               rank0, rank1, E, N, packBlocks);
  scan_part_kernel<<<nbScan, TPB, 0, stream>>>(cnt, off, bsum, N2);
  scan_addm_kernel<<<nbScan, TPB, 0, stream>>>(off, bsum, cnt, dinv, N2, nbScan);

  // fused atomic-free CSR-fill + layer-0 matmul
  fillmm0_kernel<<<fillBlocks + gridDual, TPB, 0, stream>>>(
      ei0, ei1, off, rank0, rank1, csr, E, fillBlocks, Wp, x, dinv, tab0, tab1, N, N);
  gather_kernel<<<gridGath, TPB, 0, stream>>>(tab0, tab1, dinv, off, csr,
                                              b0, b1, hbuf, stats, N, N);
  for (int i = 1; i < 3; i++) {
    mm_dual_k<<<gridDual, TPB, 0, stream>>>(Wp + (size_t)(2 * i) * 32768, hbuf,
                                            stats + (size_t)(i - 1) * 2048,
                                            gamma + (i - 1) * D, beta + (i - 1) * D,
                                            dinv, tab0, tab1, N, N, invn);
    gather_kernel<<<gridGath, TPB, 0, stream>>>(tab0, tab1, dinv, off, csr,
                                                b0 + i * D, b1 + i * D, hbuf,
                                                stats + (size_t)i * 2048, N, N);
  }
  heads3_kernel<<<gridH3, TPB, 0, stream>>>(
      Wp, hbuf, stats + (size_t)2 * 2048, gamma + 2 * D, beta + 2 * D,
      emb1_b, emb2_b, ph1_ba, ph1_bb, ph2_ba, ph2_bb, out, N, invn);
}

// Round 14
// 308.006 us; speedup vs baseline: 1.5730x; 1.0095x over previous
//
#include <hip/hip_runtime.h>
#include <cstdint>
#include <cstddef>

#define D 128

typedef __attribute__((ext_vector_type(8))) short bf16x8;
typedef __attribute__((ext_vector_type(4))) float f32x4;
typedef __attribute__((ext_vector_type(8))) _Float16 f16x8;
typedef __attribute__((ext_vector_type(4))) unsigned int u32x4;

__device__ __forceinline__ unsigned short f2bf(float f) {
  unsigned int u = __float_as_uint(f);
  unsigned int r = u + 0x7FFFu + ((u >> 16) & 1u);
  return (unsigned short)(r >> 16);
}
__device__ __forceinline__ float bf2f(unsigned short h) {
  return __uint_as_float((unsigned int)h << 16);
}
__device__ __forceinline__ float fast_tanh(float x) {
  float cx = fminf(fmaxf(x, -15.f), 15.f);
  float e = __expf(2.f * cx);
  return (e - 1.f) * __builtin_amdgcn_rcpf(e + 1.f);
}
union HU { _Float16 f; unsigned short u; };

// split 8 fp32 -> bf16 hi + bf16 lo planes via HW packed convert (RNE)
__device__ __forceinline__ void split8(const float vv[8], bf16x8& hh, bf16x8& hl) {
  u32x4 ph, pl;
#pragma unroll
  for (int i = 0; i < 4; i++) {
    unsigned int p;
    asm("v_cvt_pk_bf16_f32 %0, %1, %2" : "=v"(p) : "v"(vv[2 * i]), "v"(vv[2 * i + 1]));
    ph[i] = p;
    float r0 = vv[2 * i] - __uint_as_float(p << 16);
    float r1 = vv[2 * i + 1] - __uint_as_float(p & 0xFFFF0000u);
    unsigned int q;
    asm("v_cvt_pk_bf16_f32 %0, %1, %2" : "=v"(q) : "v"(r0), "v"(r1));
    pl[i] = q;
  }
  hh = __builtin_bit_cast(bf16x8, ph);
  hl = __builtin_bit_cast(bf16x8, pl);
}

// ---------------- fused pack (12 weight mats) + degree count (+edge ranks) ----------------
struct WPtrs { const float* w[12]; };

__global__ __launch_bounds__(256) void packcount_kernel(
    WPtrs P, unsigned short* __restrict__ Wp,
    const int* __restrict__ d0, const int* __restrict__ d1,
    int* __restrict__ cnt, int* __restrict__ rank0, int* __restrict__ rank1,
    int E, int N, int packBlocks) {
  if ((int)blockIdx.x < packBlocks) {
    int tid = blockIdx.x * 256 + threadIdx.x;  // 0..196607
    int m = tid >> 14;
    int r = tid & 16383;
    int b = r & 7, lane = (r >> 3) & 63, ks = (r >> 9) & 3, jt = r >> 11;
    int k = ks * 32 + ((lane >> 4) << 3) + b;
    int j = jt * 16 + (lane & 15);
    float w = P.w[m][k * 128 + j];
    if (m < 8) {
      unsigned short h = f2bf(w);
      Wp[m * 32768 + r] = h;
      Wp[m * 32768 + 16384 + r] = f2bf(w - bf2f(h));
    } else {
      HU hh, ll;
      hh.f = (_Float16)w;
      ll.f = (_Float16)(w - (float)hh.f);
      Wp[m * 32768 + r] = hh.u;
      Wp[m * 32768 + 16384 + r] = ll.u;
    }
  } else {
    int e = ((int)blockIdx.x - packBlocks) * 256 + threadIdx.x;
    if (e < E) {
      rank0[e] = atomicAdd(&cnt[d0[e]], 1);
      rank1[e] = atomicAdd(&cnt[N + d1[e]], 1);
    }
  }
}

// ---------------- CSR scan ----------------
__global__ __launch_bounds__(256) void scan_part_kernel(const int* __restrict__ cnt,
                                                        int* __restrict__ off,
                                                        int* __restrict__ bsum, int n2) {
  __shared__ int sh[256];
  int t = threadIdx.x;
  int i0 = blockIdx.x * 512 + 2 * t;
  int a0 = (i0 < n2) ? cnt[i0] : 0;
  int a1 = (i0 + 1 < n2) ? cnt[i0 + 1] : 0;
  int s = a0 + a1;
  sh[t] = s;
  __syncthreads();
  for (int d = 1; d < 256; d <<= 1) {
    int v = (t >= d) ? sh[t - d] : 0;
    __syncthreads();
    sh[t] += v;
    __syncthreads();
  }
  int p = sh[t] - s;
  if (i0 < n2) off[i0] = p;
  if (i0 + 1 < n2) off[i0 + 1] = p + a0;
  if (t == 255) bsum[blockIdx.x] = sh[255];
}

// merged: every block redundantly scans bsum, applies prefix, computes dinv;
// block 0 writes grand total off[n2].
__global__ __launch_bounds__(256) void scan_addm_kernel(int* __restrict__ off,
                                                        const int* __restrict__ bsum,
                                                        const int* __restrict__ cnt,
                                                        float* __restrict__ dinv,
                                                        int n2, int nb) {
  __shared__ int sh[256];
  int t = threadIdx.x;
  int s = (t < nb) ? bsum[t] : 0;
  sh[t] = s;
  __syncthreads();
  for (int d = 1; d < 256; d <<= 1) {
    int v = (t >= d) ? sh[t - d] : 0;
    __syncthreads();
    sh[t] += v;
    __syncthreads();
  }
  if (blockIdx.x == 0 && t == 0) off[n2] = sh[nb - 1];
  int add = (blockIdx.x > 0) ? sh[blockIdx.x - 1] : 0;
  int base = blockIdx.x * 512;
#pragma unroll
  for (int u = 0; u < 2; u++) {
    int i = base + t + u * 256;
    if (i < n2) {
      off[i] += add;
      dinv[i] = rsqrtf((float)cnt[i] + 1.0f);
    }
  }
}

// ---------------- dual GCN matmul body ----------------
template <int BN>
__device__ __forceinline__ void mm_dual_body(
    int bid, const unsigned short* __restrict__ Wp, const float* __restrict__ Af,
    const float* __restrict__ stats, const float* __restrict__ g0,
    const float* __restrict__ bt0, const float* __restrict__ dinv,
    _Float16* __restrict__ tab0, _Float16* __restrict__ tab1,
    int n, int N, float invn) {
  __shared__ float bnsc[128], bnsh[128];
  if (BN) {
    int t = threadIdx.x;
    if (t < 128) {
      float s = 0.f, q = 0.f;
#pragma unroll
      for (int r = 0; r < 8; r++) { s += stats[r * 128 + t]; q += stats[1024 + r * 128 + t]; }
      float mu = s * invn, var = q * invn - mu * mu;
      float sc = g0[t] * rsqrtf(var + 1e-5f);
      bnsc[t] = sc; bnsh[t] = bt0[t] - mu * sc;
    }
    __syncthreads();
  }
  constexpr int WJT = 4, WIT = 4;
  const int lane = threadIdx.x & 63;
  const int wid = threadIdx.x >> 6;
  const int wj = wid % 4, wi = wid / 4;
  const int jtbase = wj * WJT;
  const int ibase = bid * 64 + wi * WIT * 16;
  const int lrow = lane & 15, lgrp = lane >> 4;

  int node[WIT];
  bool valid[WIT];
#pragma unroll
  for (int it = 0; it < WIT; it++) {
    int i = ibase + it * 16 + lrow;
    valid[it] = (i < n);
    node[it] = valid[it] ? i : (n - 1);
  }

  f32x4 acc[WJT][WIT];
#pragma unroll
  for (int jt = 0; jt < WJT; jt++)
#pragma unroll
    for (int it = 0; it < WIT; it++) acc[jt][it] = (f32x4){0.f, 0.f, 0.f, 0.f};

#pragma unroll
  for (int ks = 0; ks < 4; ks++) {
    float sck[8], shk[8];
    if (BN) {
      int cb = ks * 32 + lgrp * 8;
#pragma unroll
      for (int c = 0; c < 8; c++) { sck[c] = bnsc[cb + c]; shk[c] = bnsh[cb + c]; }
    }
    bf16x8 awh[WJT], awl[WJT];
#pragma unroll
    for (int jt = 0; jt < WJT; jt++) {
      int jg = jtbase + jt;
      const unsigned short* base = Wp + ((jg >= 8) ? 32768 : 0);
      size_t fo = (size_t)(((jg & 7) * 4 + ks) * 64 + lane) * 8;
      awh[jt] = *(const bf16x8*)(base + fo);
      awl[jt] = *(const bf16x8*)(base + fo + 16384);
    }
#pragma unroll
    for (int it = 0; it < WIT; it++) {
      const float* src = Af + (size_t)node[it] * 128 + ks * 32 + lgrp * 8;
      float4 u0 = *(const float4*)src;
      float4 u1 = *(const float4*)(src + 4);
      float vv[8] = {u0.x, u0.y, u0.z, u0.w, u1.x, u1.y, u1.z, u1.w};
      if (BN) {
#pragma unroll
        for (int c = 0; c < 8; c++) vv[c] = fmaxf(vv[c] * sck[c] + shk[c], 0.f);
      }
      bf16x8 bhh, bhl;
      split8(vv, bhh, bhl);
#pragma unroll
      for (int jt = 0; jt < WJT; jt++) {
        acc[jt][it] = __builtin_amdgcn_mfma_f32_16x16x32_bf16(awh[jt], bhh, acc[jt][it], 0, 0, 0);
        acc[jt][it] = __builtin_amdgcn_mfma_f32_16x16x32_bf16(awl[jt], bhh, acc[jt][it], 0, 0, 0);
        acc[jt][it] = __builtin_amdgcn_mfma_f32_16x16x32_bf16(awh[jt], bhl, acc[jt][it], 0, 0, 0);
      }
    }
  }

#pragma unroll
  for (int it = 0; it < WIT; it++) {
    if (!valid[it]) continue;
    float d0v = dinv[node[it]];
    float d1v = dinv[N + node[it]];
#pragma unroll
    for (int jt = 0; jt < WJT; jt++) {
      int jg = jtbase + jt;
      float s = (jg < 8) ? d0v : d1v;
      _Float16 o[4];
#pragma unroll
      for (int c = 0; c < 4; c++) o[c] = (_Float16)(acc[jt][it][c] * s);
      _Float16* base = (jg < 8)
          ? (tab0 + (size_t)node[it] * 128 + jg * 16)
          : (tab1 + (size_t)node[it] * 128 + (jg - 8) * 16);
      *(uint2*)(base + lgrp * 4) = *(uint2*)o;
    }
  }
}

__global__ __launch_bounds__(256) void mm_dual_k(
    const unsigned short* __restrict__ Wp, const float* __restrict__ Af,
    const float* __restrict__ stats, const float* __restrict__ g0,
    const float* __restrict__ bt0, const float* __restrict__ dinv,
    _Float16* __restrict__ tab0, _Float16* __restrict__ tab1,
    int n, int N, float invn) {
  mm_dual_body<1>(blockIdx.x, Wp, Af, stats, g0, bt0, dinv, tab0, tab1, n, N, invn);
}

// fused: atomic-free CSR fill + layer-0 mm_dual
__global__ __launch_bounds__(256) void fillmm0_kernel(
    const int* __restrict__ ei0, const int* __restrict__ ei1,
    const int* __restrict__ off, const int* __restrict__ rank0,
    const int* __restrict__ rank1, int* __restrict__ csr,
    int E, int fillBlocks,
    const unsigned short* __restrict__ Wp, const float* __restrict__ x,
    const float* __restrict__ dinv, _Float16* __restrict__ tab0,
    _Float16* __restrict__ tab1, int n, int N) {
  if ((int)blockIdx.x < fillBlocks) {
    int e = blockIdx.x * 256 + threadIdx.x;
    if (e < E) {
      int s = ei0[e], d = ei0[E + e];
      csr[off[d] + rank0[e]] = s;
      s = ei1[e]; d = ei1[E + e];
      csr[off[N + d] + rank1[e]] = s;
    }
  } else {
    mm_dual_body<0>(blockIdx.x - fillBlocks, Wp, x, nullptr, nullptr, nullptr,
                    dinv, tab0, tab1, n, N, 0.f);
  }
}

// ---------------- gather + fused BN stats ----------------
__global__ __launch_bounds__(256) void gather_kernel(
    const _Float16* __restrict__ tab0, const _Float16* __restrict__ tab1,
    const float* __restrict__ dinv, const int* __restrict__ off,
    const int* __restrict__ csr,
    const float* __restrict__ b0, const float* __restrict__ b1,
    float* __restrict__ outh, float* __restrict__ stats, int n, int N) {
  __shared__ float reds[4][128];
  __shared__ float redq[4][128];
  int t = threadIdx.x;
  int g = t >> 4, l = t & 15;
  int node = blockIdx.x * 16 + g;
  bool valid = node < n;
  int nd = valid ? node : 0;
  const f16x8* t0 = (const f16x8*)tab0;
  const f16x8* t1 = (const f16x8*)tab1;
  float s0[8] = {0,0,0,0,0,0,0,0}, s1[8] = {0,0,0,0,0,0,0,0};
  if (valid) {
    f16x8 v = t0[(size_t)nd * 16 + l];
#pragma unroll
    for (int c = 0; c < 8; c++) s0[c] = (float)v[c];
    v = t1[(size_t)nd * 16 + l];
#pragma unroll
    for (int c = 0; c < 8; c++) s1[c] = (float)v[c];
  }
  int a = valid ? off[nd] : 0, b = valid ? off[nd + 1] : 0;
  int j = a;
  for (; j + 3 < b; j += 4) {
    int i0 = csr[j], i1 = csr[j + 1], i2 = csr[j + 2], i3 = csr[j + 3];
    f16x8 v0 = t0[(size_t)i0 * 16 + l];
    f16x8 v1 = t0[(size_t)i1 * 16 + l];
    f16x8 v2 = t0[(size_t)i2 * 16 + l];
    f16x8 v3 = t0[(size_t)i3 * 16 + l];
#pragma unroll
    for (int c = 0; c < 8; c++)
      s0[c] += ((float)v0[c] + (float)v1[c]) + ((float)v2[c] + (float)v3[c]);
  }
  for (; j < b; j++) {
    f16x8 va = t0[(size_t)csr[j] * 16 + l];
#pragma unroll
    for (int c = 0; c < 8; c++) s0[c] += (float)va[c];
  }
  a = valid ? off[N + nd] : 0; b = valid ? off[N + nd + 1] : 0;
  j = a;
  for (; j + 3 < b; j += 4) {
    int i0 = csr[j], i1 = csr[j + 1], i2 = csr[j + 2], i3 = csr[j + 3];
    f16x8 v0 = t1[(size_t)i0 * 16 + l];
    f16x8 v1 = t1[(size_t)i1 * 16 + l];
    f16x8 v2 = t1[(size_t)i2 * 16 + l];
    f16x8 v3 = t1[(size_t)i3 * 16 + l];
#pragma unroll
    for (int c = 0; c < 8; c++)
      s1[c] += ((float)v0[c] + (float)v1[c]) + ((float)v2[c] + (float)v3[c]);
  }
  for (; j < b; j++) {
    f16x8 va = t1[(size_t)csr[j] * 16 + l];
#pragma unroll
    for (int c = 0; c < 8; c++) s1[c] += (float)va[c];
  }
  float o[8] = {0,0,0,0,0,0,0,0};
  if (valid) {
    float d0 = dinv[nd], d1 = dinv[N + nd];
    const float4* B0 = (const float4*)(b0 + l * 8);
    const float4* B1 = (const float4*)(b1 + l * 8);
    float4 ba0 = B0[0], ba1 = B0[1], bb0 = B1[0], bb1 = B1[1];
    float bs[8] = {ba0.x + bb0.x, ba0.y + bb0.y, ba0.z + bb0.z, ba0.w + bb0.w,
                   ba1.x + bb1.x, ba1.y + bb1.y, ba1.z + bb1.z, ba1.w + bb1.w};
#pragma unroll
    for (int c = 0; c < 8; c++) o[c] = d0 * s0[c] + d1 * s1[c] + bs[c];
    float* dst = outh + (size_t)nd * 128 + l * 8;
    *(float4*)dst = make_float4(o[0], o[1], o[2], o[3]);
    *(float4*)(dst + 4) = make_float4(o[4], o[5], o[6], o[7]);
  }
  float sv[8], q[8];
#pragma unroll
  for (int c = 0; c < 8; c++) { sv[c] = o[c]; q[c] = o[c] * o[c]; }
#pragma unroll
  for (int c = 0; c < 8; c++) {
    sv[c] += __shfl_xor(sv[c], 16); sv[c] += __shfl_xor(sv[c], 32);
    q[c] += __shfl_xor(q[c], 16);  q[c] += __shfl_xor(q[c], 32);
  }
  int lane = t & 63, wid = t >> 6;
  if (lane < 16) {
#pragma unroll
    for (int c = 0; c < 8; c++) { reds[wid][lane * 8 + c] = sv[c]; redq[wid][lane * 8 + c] = q[c]; }
  }
  __syncthreads();
  if (t < 128) {
    float ts = reds[0][t] + reds[1][t] + reds[2][t] + reds[3][t];
    float tq = redq[0][t] + redq[1][t] + redq[2][t] + redq[3][t];
    int cp = blockIdx.x & 7;
    atomicAdd(&stats[cp * 128 + t], ts);
    atomicAdd(&stats[1024 + cp * 128 + t], tq);
  }
}

// ---------------- per-head fused chain: e->t->p, 64 nodes, 128 threads (2 waves) ----
#define TPH 136
__global__ __launch_bounds__(128) void heads_kernel(
    const unsigned short* __restrict__ Wp,
    const float* __restrict__ h, const float* __restrict__ stats,
    const float* __restrict__ g2, const float* __restrict__ bt2,
    const float* __restrict__ emb1_b, const float* __restrict__ emb2_b,
    const float* __restrict__ ph1_ba, const float* __restrict__ ph1_bb,
    const float* __restrict__ ph2_ba, const float* __restrict__ ph2_bb,
    float* __restrict__ out, int n, float invn) {
  __shared__ float bnsc[128], bnsh[128];
  __shared__ _Float16 tile[64 * TPH];
  __shared__ float l2red[4][16][2];
  const int t = threadIdx.x;
  {
    float s = 0.f, q = 0.f;
#pragma unroll
    for (int r = 0; r < 8; r++) { s += stats[r * 128 + t]; q += stats[1024 + r * 128 + t]; }
    float mu = s * invn, var = q * invn - mu * mu;
    float sc = g2[t] * rsqrtf(var + 1e-5f);
    bnsc[t] = sc; bnsh[t] = bt2[t] - mu * sc;
  }
  __syncthreads();

  const int lane = t & 63;
  const int wj = t >> 6;                 // feature half (2 waves)
  const int wh = blockIdx.x & 1;         // head
  const int base = ((int)blockIdx.x >> 1) * 64;
  const int lrow = lane & 15, lgrp = lane >> 4;
  const int jtbase = wj * 4;
  const size_t ND = (size_t)n * 128;

  int node[4];
  bool valid[4];
#pragma unroll
  for (int it = 0; it < 4; it++) {
    int i = base + it * 16 + lrow;
    valid[it] = (i < n);
    node[it] = valid[it] ? i : (n - 1);
  }

  f32x4 acc[4][4];
  const unsigned short* slot;
  const float* bias;

  // stage 1: e = tanh(BN(h) @ W[6+wh] + emb_b)  (bf16 split)
  slot = Wp + (size_t)(6 + wh) * 32768;
  bias = wh ? emb2_b : emb1_b;
#pragma unroll
  for (int jt = 0; jt < 4; jt++) {
    float4 b4 = *(const float4*)(bias + (jtbase + jt) * 16 + lgrp * 4);
#pragma unroll
    for (int it = 0; it < 4; it++) acc[jt][it] = (f32x4){b4.x, b4.y, b4.z, b4.w};
  }
#pragma unroll
  for (int ks = 0; ks < 4; ks++) {
    int cb = ks * 32 + lgrp * 8;
    float sck[8], shk[8];
#pragma unroll
    for (int c = 0; c < 8; c++) { sck[c] = bnsc[cb + c]; shk[c] = bnsh[cb + c]; }
    bf16x8 awh[4], awl[4];
#pragma unroll
    for (int jt = 0; jt < 4; jt++) {
      size_t fo = (size_t)(((jtbase + jt) * 4 + ks) * 64 + lane) * 8;
      awh[jt] = *(const bf16x8*)(slot + fo);
      awl[jt] = *(const bf16x8*)(slot + fo + 16384);
    }
#pragma unroll
    for (int it = 0; it < 4; it++) {
      const float* src = h + (size_t)node[it] * 128 + cb;
      float4 u0 = *(const float4*)src;
      float4 u1 = *(const float4*)(src + 4);
      float vv[8] = {u0.x, u0.y, u0.z, u0.w, u1.x, u1.y, u1.z, u1.w};
#pragma unroll
      for (int c = 0; c < 8; c++) vv[c] = vv[c] * sck[c] + shk[c];
      bf16x8 bhh, bhl;
      split8(vv, bhh, bhl);
#pragma unroll
      for (int jt = 0; jt < 4; jt++) {
        acc[jt][it] = __builtin_amdgcn_mfma_f32_16x16x32_bf16(awh[jt], bhh, acc[jt][it], 0, 0, 0);
        acc[jt][it] = __builtin_amdgcn_mfma_f32_16x16x32_bf16(awl[jt], bhh, acc[jt][it], 0, 0, 0);
        acc[jt][it] = __builtin_amdgcn_mfma_f32_16x16x32_bf16(awh[jt], bhl, acc[jt][it], 0, 0, 0);
      }
    }
  }
#pragma unroll
  for (int jt = 0; jt < 4; jt++)
#pragma unroll
    for (int it = 0; it < 4; it++)
#pragma unroll
      for (int c = 0; c < 4; c++) acc[jt][it][c] = fast_tanh(acc[jt][it][c]);

  float rsv[4];
  if (wh == 1) {  // e2 l2norm (cross-wave reduce)
#pragma unroll
    for (int it = 0; it < 4; it++) {
      float rs = 0.f;
#pragma unroll
      for (int jt = 0; jt < 4; jt++)
#pragma unroll
        for (int c = 0; c < 4; c++) rs += acc[jt][it][c] * acc[jt][it][c];
      rs += __shfl_xor(rs, 16);
      rs += __shfl_xor(rs, 32);
      rsv[it] = rs;
      if (lane < 16) l2red[it][lane][wj] = rs;
    }
    __syncthreads();
#pragma unroll
    for (int it = 0; it < 4; it++) {
      float full = rsv[it] + l2red[it][lrow][wj ^ 1];
      float scl = 1.f / fmaxf(sqrtf(full), 1e-12f);
#pragma unroll
      for (int jt = 0; jt < 4; jt++)
#pragma unroll
        for (int c = 0; c < 4; c++) acc[jt][it][c] *= scl;
    }
  }
#pragma unroll
  for (int it = 0; it < 4; it++) {
#pragma unroll
    for (int jt = 0; jt < 4; jt++) {
      if (valid[it])
        *(float4*)(out + (size_t)wh * ND + (size_t)node[it] * 128 + (jtbase + jt) * 16 + lgrp * 4) =
            make_float4(acc[jt][it][0], acc[jt][it][1], acc[jt][it][2], acc[jt][it][3]);
      _Float16 o4[4];
#pragma unroll
      for (int c = 0; c < 4; c++) o4[c] = (_Float16)acc[jt][it][c];
      *(uint2*)(tile + (it * 16 + lrow) * TPH + (jtbase + jt) * 16 + lgrp * 4) = *(uint2*)o4;
    }
  }
  __syncthreads();

  // stage 2: t = relu(e @ W[8+2wh] + ph_ba)  (f16 hi/lo)
  slot = Wp + (size_t)(8 + 2 * wh) * 32768;
  bias = wh ? ph2_ba : ph1_ba;
#pragma unroll
  for (int jt = 0; jt < 4; jt++) {
    float4 b4 = *(const float4*)(bias + (jtbase + jt) * 16 + lgrp * 4);
#pragma unroll
    for (int it = 0; it < 4; it++) acc[jt][it] = (f32x4){b4.x, b4.y, b4.z, b4.w};
  }
#pragma unroll
  for (int ks = 0; ks < 4; ks++) {
    f16x8 awh[4], awl[4];
#pragma unroll
    for (int jt = 0; jt < 4; jt++) {
      size_t fo = (size_t)(((jtbase + jt) * 4 + ks) * 64 + lane) * 8;
      awh[jt] = *(const f16x8*)(slot + fo);
      awl[jt] = *(const f16x8*)(slot + fo + 16384);
    }
#pragma unroll
    for (int it = 0; it < 4; it++) {
      f16x8 bh = *(const f16x8*)(tile + (it * 16 + lrow) * TPH + ks * 32 + lgrp * 8);
#pragma unroll
      for (int jt = 0; jt < 4; jt++) {
        acc[jt][it] = __builtin_amdgcn_mfma_f32_16x16x32_f16(awh[jt], bh, acc[jt][it], 0, 0, 0);
        acc[jt][it] = __builtin_amdgcn_mfma_f32_16x16x32_f16(awl[jt], bh, acc[jt][it], 0, 0, 0);
      }
    }
  }
#pragma unroll
  for (int jt = 0; jt < 4; jt++)
#pragma unroll
    for (int it = 0; it < 4; it++)
#pragma unroll
      for (int c = 0; c < 4; c++) acc[jt][it][c] = fmaxf(acc[jt][it][c], 0.f);
  __syncthreads();
#pragma unroll
  for (int it = 0; it < 4; it++)
#pragma unroll
    for (int jt = 0; jt < 4; jt++) {
      _Float16 o4[4];
#pragma unroll
      for (int c = 0; c < 4; c++) o4[c] = (_Float16)acc[jt][it][c];
      *(uint2*)(tile + (it * 16 + lrow) * TPH + (jtbase + jt) * 16 + lgrp * 4) = *(uint2*)o4;
    }
  __syncthreads();

  // stage 3: p = l2norm(t @ W[9+2wh] + ph_bb)  (f16 hi/lo)
  slot = Wp + (size_t)(9 + 2 * wh) * 32768;
  bias = wh ? ph2_bb : ph1_bb;
#pragma unroll
  for (int jt = 0; jt < 4; jt++) {
    float4 b4 = *(const float4*)(bias + (jtbase + jt) * 16 + lgrp * 4);
#pragma unroll
    for (int it = 0; it < 4; it++) acc[jt][it] = (f32x4){b4.x, b4.y, b4.z, b4.w};
  }
#pragma unroll
  for (int ks = 0; ks < 4; ks++) {
    f16x8 awh[4], awl[4];
#pragma unroll
    for (int jt = 0; jt < 4; jt++) {
      size_t fo = (size_t)(((jtbase + jt) * 4 + ks) * 64 + lane) * 8;
      awh[jt] = *(const f16x8*)(slot + fo);
      awl[jt] = *(const f16x8*)(slot + fo + 16384);
    }
#pragma unroll
    for (int it = 0; it < 4; it++) {
      f16x8 bh = *(const f16x8*)(tile + (it * 16 + lrow) * TPH + ks * 32 + lgrp * 8);
#pragma unroll
      for (int jt = 0; jt < 4; jt++) {
        acc[jt][it] = __builtin_amdgcn_mfma_f32_16x16x32_f16(awh[jt], bh, acc[jt][it], 0, 0, 0);
        acc[jt][it] = __builtin_amdgcn_mfma_f32_16x16x32_f16(awl[jt], bh, acc[jt][it], 0, 0, 0);
      }
    }
  }
#pragma unroll
  for (int it = 0; it < 4; it++) {
    float rs = 0.f;
#pragma unroll
    for (int jt = 0; jt < 4; jt++)
#pragma unroll
      for (int c = 0; c < 4; c++) rs += acc[jt][it][c] * acc[jt][it][c];
    rs += __shfl_xor(rs, 16);
    rs += __shfl_xor(rs, 32);
    rsv[it] = rs;
    if (lane < 16) l2red[it][lane][wj] = rs;
  }
  __syncthreads();
#pragma unroll
  for (int it = 0; it < 4; it++) {
    float full = rsv[it] + l2red[it][lrow][wj ^ 1];
    float scl = 1.f / fmaxf(sqrtf(full), 1e-12f);
    if (!valid[it]) continue;
#pragma unroll
    for (int jt = 0; jt < 4; jt++)
      *(float4*)(out + (size_t)(2 + wh) * ND + (size_t)node[it] * 128 + (jtbase + jt) * 16 + lgrp * 4) =
          make_float4(acc[jt][it][0] * scl, acc[jt][it][1] * scl,
                      acc[jt][it][2] * scl, acc[jt][it][3] * scl);
  }
}

// ---------------- launch ----------------
extern "C" void kernel_launch(void* const* d_in, const int* in_sizes, int n_in,
                              void* d_out, int out_size, void* d_ws, size_t ws_size,
                              hipStream_t stream) {
  const float* x      = (const float*)d_in[0];
  const int*   ei0    = (const int*)d_in[1];
  const int*   ei1    = (const int*)d_in[2];
  const float* W0     = (const float*)d_in[3];
  const float* b0     = (const float*)d_in[4];
  const float* W1     = (const float*)d_in[5];
  const float* b1     = (const float*)d_in[6];
  const float* gamma  = (const float*)d_in[7];
  const float* beta   = (const float*)d_in[8];
  const float* emb1_W = (const float*)d_in[9];
  const float* emb1_b = (const float*)d_in[10];
  const float* emb2_W = (const float*)d_in[11];
  const float* emb2_b = (const float*)d_in[12];
  const float* ph1_Wa = (const float*)d_in[13];
  const float* ph1_ba = (const float*)d_in[14];
  const float* ph1_Wb = (const float*)d_in[15];
  const float* ph1_bb = (const float*)d_in[16];
  const float* ph2_Wa = (const float*)d_in[17];
  const float* ph2_ba = (const float*)d_in[18];
  const float* ph2_Wb = (const float*)d_in[19];
  const float* ph2_bb = (const float*)d_in[20];

  const int N = in_sizes[0] / D;
  const int E = in_sizes[1] / 2;
  const int N2 = 2 * N;
  const size_t ND = (size_t)N * D;
  const float invn = 1.0f / (float)N;
  float* out = (float*)d_out;

  char* p = (char*)d_ws;
  auto carve = [&](size_t bytes) -> void* {
    void* r = (void*)p;
    p += (bytes + 255) & ~(size_t)255;
    return r;
  };
  int*   cnt   = (int*)carve((size_t)N2 * 4);
  float* stats = (float*)carve((size_t)3 * 2048 * 4);   // [layer][2][8][128]
  size_t zbytes = (size_t)((char*)(stats + 3 * 2048) - (char*)cnt);
  int*   off   = (int*)carve((size_t)(N2 + 1) * 4);
  float* dinv  = (float*)carve((size_t)N2 * 4);
  int*   csr   = (int*)carve((size_t)2 * E * 4);
  int*   rank0 = (int*)carve((size_t)E * 4);
  int*   rank1 = (int*)carve((size_t)E * 4);
  int*   bsum  = (int*)carve(256 * 4);
  unsigned short* Wp = (unsigned short*)carve((size_t)12 * 32768 * 2);
  float* hbuf = (float*)carve(4 * ND);
  _Float16* tab0 = (_Float16*)carve(2 * ND);
  _Float16* tab1 = (_Float16*)carve(2 * ND);

  const int TPB = 256;
  const int packBlocks = 768;
  const int gridPC = packBlocks + (E + TPB - 1) / TPB;
  const int fillBlocks = (E + TPB - 1) / TPB;
  const int nbScan = (N2 + 511) / 512;
  const int gridDual = (N + 63) / 64;
  const int gridGath = (N + 15) / 16;
  const int gridHd = 2 * ((N + 63) / 64);

  WPtrs P;
  P.w[0] = W0;                     P.w[1] = W1;
  P.w[2] = W0 + (size_t)D * D;     P.w[3] = W1 + (size_t)D * D;
  P.w[4] = W0 + (size_t)2 * D * D; P.w[5] = W1 + (size_t)2 * D * D;
  P.w[6] = emb1_W; P.w[7] = emb2_W;
  P.w[8] = ph1_Wa; P.w[9] = ph1_Wb;
  P.w[10] = ph2_Wa; P.w[11] = ph2_Wb;

  hipMemsetAsync(cnt, 0, zbytes, stream);
  packcount_kernel<<<gridPC, TPB, 0, stream>>>(P, Wp, ei0 + E, ei1 + E, cnt,
                                               rank0, rank1, E, N, packBlocks);
  scan_part_kernel<<<nbScan, TPB, 0, stream>>>(cnt, off, bsum, N2);
  scan_addm_kernel<<<nbScan, TPB, 0, stream>>>(off, bsum, cnt, dinv, N2, nbScan);

  fillmm0_kernel<<<fillBlocks + gridDual, TPB, 0, stream>>>(
      ei0, ei1, off, rank0, rank1, csr, E, fillBlocks, Wp, x, dinv, tab0, tab1, N, N);
  gather_kernel<<<gridGath, TPB, 0, stream>>>(tab0, tab1, dinv, off, csr,
                                              b0, b1, hbuf, stats, N, N);
  for (int i = 1; i < 3; i++) {
    mm_dual_k<<<gridDual, TPB, 0, stream>>>(Wp + (size_t)(2 * i) * 32768, hbuf,
                                            stats + (size_t)(i - 1) * 2048,
                                            gamma + (i - 1) * D, beta + (i - 1) * D,
                                            dinv, tab0, tab1, N, N, invn);
    gather_kernel<<<gridGath, TPB, 0, stream>>>(tab0, tab1, dinv, off, csr,
                                                b0 + i * D, b1 + i * D, hbuf,
                                                stats + (size_t)i * 2048, N, N);
  }
  heads_kernel<<<gridHd, 128, 0, stream>>>(
      Wp, hbuf, stats + (size_t)2 * 2048, gamma + 2 * D, beta + 2 * D,
      emb1_b, emb2_b, ph1_ba, ph1_bb, ph2_ba, ph2_bb, out, N, invn);
}

// Round 16
// 307.552 us; speedup vs baseline: 1.5753x; 1.0015x over previous
//
#include <hip/hip_runtime.h>
#include <cstdint>
#include <cstddef>

#define D 128

typedef __attribute__((ext_vector_type(8))) short bf16x8;
typedef __attribute__((ext_vector_type(4))) float f32x4;
typedef __attribute__((ext_vector_type(8))) _Float16 f16x8;
typedef __attribute__((ext_vector_type(4))) unsigned int u32x4;

__device__ __forceinline__ unsigned short f2bf(float f) {
  unsigned int u = __float_as_uint(f);
  unsigned int r = u + 0x7FFFu + ((u >> 16) & 1u);
  return (unsigned short)(r >> 16);
}
__device__ __forceinline__ float bf2f(unsigned short h) {
  return __uint_as_float((unsigned int)h << 16);
}
__device__ __forceinline__ float fast_tanh(float x) {
  float cx = fminf(fmaxf(x, -15.f), 15.f);
  float e = __expf(2.f * cx);
  return (e - 1.f) * __builtin_amdgcn_rcpf(e + 1.f);
}
union HU { _Float16 f; unsigned short u; };

// split 8 fp32 -> bf16 hi + bf16 lo planes via HW packed convert (RNE)
__device__ __forceinline__ void split8(const float vv[8], bf16x8& hh, bf16x8& hl) {
  u32x4 ph, pl;
#pragma unroll
  for (int i = 0; i < 4; i++) {
    unsigned int p;
    asm("v_cvt_pk_bf16_f32 %0, %1, %2" : "=v"(p) : "v"(vv[2 * i]), "v"(vv[2 * i + 1]));
    ph[i] = p;
    float r0 = vv[2 * i] - __uint_as_float(p << 16);
    float r1 = vv[2 * i + 1] - __uint_as_float(p & 0xFFFF0000u);
    unsigned int q;
    asm("v_cvt_pk_bf16_f32 %0, %1, %2" : "=v"(q) : "v"(r0), "v"(r1));
    pl[i] = q;
  }
  hh = __builtin_bit_cast(bf16x8, ph);
  hl = __builtin_bit_cast(bf16x8, pl);
}

// ---------------- fused pack (12 weight mats) + degree count (+edge ranks) ----------------
struct WPtrs { const float* w[12]; };

__global__ __launch_bounds__(256) void packcount_kernel(
    WPtrs P, unsigned short* __restrict__ Wp,
    const int* __restrict__ d0, const int* __restrict__ d1,
    int* __restrict__ cnt, int* __restrict__ rank0, int* __restrict__ rank1,
    int E, int N, int packBlocks) {
  if ((int)blockIdx.x < packBlocks) {
    int tid = blockIdx.x * 256 + threadIdx.x;  // 0..196607
    int m = tid >> 14;
    int r = tid & 16383;
    int b = r & 7, lane = (r >> 3) & 63, ks = (r >> 9) & 3, jt = r >> 11;
    int k = ks * 32 + ((lane >> 4) << 3) + b;
    int j = jt * 16 + (lane & 15);
    float w = P.w[m][k * 128 + j];
    if (m < 8) {
      unsigned short h = f2bf(w);
      Wp[m * 32768 + r] = h;
      Wp[m * 32768 + 16384 + r] = f2bf(w - bf2f(h));
    } else {
      HU hh, ll;
      hh.f = (_Float16)w;
      ll.f = (_Float16)(w - (float)hh.f);
      Wp[m * 32768 + r] = hh.u;
      Wp[m * 32768 + 16384 + r] = ll.u;
    }
  } else {
    int e = ((int)blockIdx.x - packBlocks) * 256 + threadIdx.x;
    if (e < E) {
      rank0[e] = atomicAdd(&cnt[d0[e]], 1);
      rank1[e] = atomicAdd(&cnt[N + d1[e]], 1);
    }
  }
}

// ---------------- CSR scan ----------------
__global__ __launch_bounds__(256) void scan_part_kernel(const int* __restrict__ cnt,
                                                        int* __restrict__ off,
                                                        int* __restrict__ bsum, int n2) {
  __shared__ int sh[256];
  int t = threadIdx.x;
  int i0 = blockIdx.x * 512 + 2 * t;
  int a0 = (i0 < n2) ? cnt[i0] : 0;
  int a1 = (i0 + 1 < n2) ? cnt[i0 + 1] : 0;
  int s = a0 + a1;
  sh[t] = s;
  __syncthreads();
  for (int d = 1; d < 256; d <<= 1) {
    int v = (t >= d) ? sh[t - d] : 0;
    __syncthreads();
    sh[t] += v;
    __syncthreads();
  }
  int p = sh[t] - s;
  if (i0 < n2) off[i0] = p;
  if (i0 + 1 < n2) off[i0 + 1] = p + a0;
  if (t == 255) bsum[blockIdx.x] = sh[255];
}

// merged: every block redundantly scans bsum, applies prefix, computes dinv;
// block 0 writes grand total off[n2].
__global__ __launch_bounds__(256) void scan_addm_kernel(int* __restrict__ off,
                                                        const int* __restrict__ bsum,
                                                        const int* __restrict__ cnt,
                                                        float* __restrict__ dinv,
                                                        int n2, int nb) {
  __shared__ int sh[256];
  int t = threadIdx.x;
  int s = (t < nb) ? bsum[t] : 0;
  sh[t] = s;
  __syncthreads();
  for (int d = 1; d < 256; d <<= 1) {
    int v = (t >= d) ? sh[t - d] : 0;
    __syncthreads();
    sh[t] += v;
    __syncthreads();
  }
  if (blockIdx.x == 0 && t == 0) off[n2] = sh[nb - 1];
  int add = (blockIdx.x > 0) ? sh[blockIdx.x - 1] : 0;
  int base = blockIdx.x * 512;
#pragma unroll
  for (int u = 0; u < 2; u++) {
    int i = base + t + u * 256;
    if (i < n2) {
      off[i] += add;
      dinv[i] = rsqrtf((float)cnt[i] + 1.0f);
    }
  }
}

// ---------------- dual GCN matmul body ----------------
template <int BN>
__device__ __forceinline__ void mm_dual_body(
    int bid, const unsigned short* __restrict__ Wp, const float* __restrict__ Af,
    const float* __restrict__ stats, const float* __restrict__ g0,
    const float* __restrict__ bt0, const float* __restrict__ dinv,
    _Float16* __restrict__ tab0, _Float16* __restrict__ tab1,
    int n, int N, float invn) {
  __shared__ float bnsc[128], bnsh[128];
  if (BN) {
    int t = threadIdx.x;
    if (t < 128) {
      float s = 0.f, q = 0.f;
#pragma unroll
      for (int r = 0; r < 8; r++) { s += stats[r * 128 + t]; q += stats[1024 + r * 128 + t]; }
      float mu = s * invn, var = q * invn - mu * mu;
      float sc = g0[t] * rsqrtf(var + 1e-5f);
      bnsc[t] = sc; bnsh[t] = bt0[t] - mu * sc;
    }
    __syncthreads();
  }
  constexpr int WJT = 4, WIT = 4;
  const int lane = threadIdx.x & 63;
  const int wid = threadIdx.x >> 6;
  const int wj = wid % 4, wi = wid / 4;
  const int jtbase = wj * WJT;
  const int ibase = bid * 64 + wi * WIT * 16;
  const int lrow = lane & 15, lgrp = lane >> 4;

  int node[WIT];
  bool valid[WIT];
#pragma unroll
  for (int it = 0; it < WIT; it++) {
    int i = ibase + it * 16 + lrow;
    valid[it] = (i < n);
    node[it] = valid[it] ? i : (n - 1);
  }

  f32x4 acc[WJT][WIT];
#pragma unroll
  for (int jt = 0; jt < WJT; jt++)
#pragma unroll
    for (int it = 0; it < WIT; it++) acc[jt][it] = (f32x4){0.f, 0.f, 0.f, 0.f};

#pragma unroll
  for (int ks = 0; ks < 4; ks++) {
    float sck[8], shk[8];
    if (BN) {
      int cb = ks * 32 + lgrp * 8;
#pragma unroll
      for (int c = 0; c < 8; c++) { sck[c] = bnsc[cb + c]; shk[c] = bnsh[cb + c]; }
    }
    bf16x8 awh[WJT], awl[WJT];
#pragma unroll
    for (int jt = 0; jt < WJT; jt++) {
      int jg = jtbase + jt;
      const unsigned short* base = Wp + ((jg >= 8) ? 32768 : 0);
      size_t fo = (size_t)(((jg & 7) * 4 + ks) * 64 + lane) * 8;
      awh[jt] = *(const bf16x8*)(base + fo);
      awl[jt] = *(const bf16x8*)(base + fo + 16384);
    }
#pragma unroll
    for (int it = 0; it < WIT; it++) {
      const float* src = Af + (size_t)node[it] * 128 + ks * 32 + lgrp * 8;
      float4 u0 = *(const float4*)src;
      float4 u1 = *(const float4*)(src + 4);
      float vv[8] = {u0.x, u0.y, u0.z, u0.w, u1.x, u1.y, u1.z, u1.w};
      if (BN) {
#pragma unroll
        for (int c = 0; c < 8; c++) vv[c] = fmaxf(vv[c] * sck[c] + shk[c], 0.f);
      }
      bf16x8 bhh, bhl;
      split8(vv, bhh, bhl);
#pragma unroll
      for (int jt = 0; jt < WJT; jt++) {
        acc[jt][it] = __builtin_amdgcn_mfma_f32_16x16x32_bf16(awh[jt], bhh, acc[jt][it], 0, 0, 0);
        acc[jt][it] = __builtin_amdgcn_mfma_f32_16x16x32_bf16(awl[jt], bhh, acc[jt][it], 0, 0, 0);
        acc[jt][it] = __builtin_amdgcn_mfma_f32_16x16x32_bf16(awh[jt], bhl, acc[jt][it], 0, 0, 0);
      }
    }
  }

#pragma unroll
  for (int it = 0; it < WIT; it++) {
    if (!valid[it]) continue;
    float d0v = dinv[node[it]];
    float d1v = dinv[N + node[it]];
#pragma unroll
    for (int jt = 0; jt < WJT; jt++) {
      int jg = jtbase + jt;
      float s = (jg < 8) ? d0v : d1v;
      _Float16 o[4];
#pragma unroll
      for (int c = 0; c < 4; c++) o[c] = (_Float16)(acc[jt][it][c] * s);
      _Float16* base = (jg < 8)
          ? (tab0 + (size_t)node[it] * 128 + jg * 16)
          : (tab1 + (size_t)node[it] * 128 + (jg - 8) * 16);
      *(uint2*)(base + lgrp * 4) = *(uint2*)o;
    }
  }
}

__global__ __launch_bounds__(256) void mm_dual_k(
    const unsigned short* __restrict__ Wp, const float* __restrict__ Af,
    const float* __restrict__ stats, const float* __restrict__ g0,
    const float* __restrict__ bt0, const float* __restrict__ dinv,
    _Float16* __restrict__ tab0, _Float16* __restrict__ tab1,
    int n, int N, float invn) {
  mm_dual_body<1>(blockIdx.x, Wp, Af, stats, g0, bt0, dinv, tab0, tab1, n, N, invn);
}

// fused: atomic-free CSR fill + layer-0 mm_dual
__global__ __launch_bounds__(256) void fillmm0_kernel(
    const int* __restrict__ ei0, const int* __restrict__ ei1,
    const int* __restrict__ off, const int* __restrict__ rank0,
    const int* __restrict__ rank1, int* __restrict__ csr,
    int E, int fillBlocks,
    const unsigned short* __restrict__ Wp, const float* __restrict__ x,
    const float* __restrict__ dinv, _Float16* __restrict__ tab0,
    _Float16* __restrict__ tab1, int n, int N) {
  if ((int)blockIdx.x < fillBlocks) {
    int e = blockIdx.x * 256 + threadIdx.x;
    if (e < E) {
      int s = ei0[e], d = ei0[E + e];
      csr[off[d] + rank0[e]] = s;
      s = ei1[e]; d = ei1[E + e];
      csr[off[N + d] + rank1[e]] = s;
    }
  } else {
    mm_dual_body<0>(blockIdx.x - fillBlocks, Wp, x, nullptr, nullptr, nullptr,
                    dinv, tab0, tab1, n, N, 0.f);
  }
}

// ---------------- gather + fused BN stats ----------------
__global__ __launch_bounds__(256) void gather_kernel(
    const _Float16* __restrict__ tab0, const _Float16* __restrict__ tab1,
    const float* __restrict__ dinv, const int* __restrict__ off,
    const int* __restrict__ csr,
    const float* __restrict__ b0, const float* __restrict__ b1,
    float* __restrict__ outh, float* __restrict__ stats, int n, int N) {
  __shared__ float reds[4][128];
  __shared__ float redq[4][128];
  int t = threadIdx.x;
  int g = t >> 4, l = t & 15;
  int node = blockIdx.x * 16 + g;
  bool valid = node < n;
  int nd = valid ? node : 0;
  const f16x8* t0 = (const f16x8*)tab0;
  const f16x8* t1 = (const f16x8*)tab1;
  float s0[8] = {0,0,0,0,0,0,0,0}, s1[8] = {0,0,0,0,0,0,0,0};
  if (valid) {
    f16x8 v = t0[(size_t)nd * 16 + l];
#pragma unroll
    for (int c = 0; c < 8; c++) s0[c] = (float)v[c];
    v = t1[(size_t)nd * 16 + l];
#pragma unroll
    for (int c = 0; c < 8; c++) s1[c] = (float)v[c];
  }
  int a = valid ? off[nd] : 0, b = valid ? off[nd + 1] : 0;
  int j = a;
  for (; j + 3 < b; j += 4) {
    int i0 = csr[j], i1 = csr[j + 1], i2 = csr[j + 2], i3 = csr[j + 3];
    f16x8 v0 = t0[(size_t)i0 * 16 + l];
    f16x8 v1 = t0[(size_t)i1 * 16 + l];
    f16x8 v2 = t0[(size_t)i2 * 16 + l];
    f16x8 v3 = t0[(size_t)i3 * 16 + l];
#pragma unroll
    for (int c = 0; c < 8; c++)
      s0[c] += ((float)v0[c] + (float)v1[c]) + ((float)v2[c] + (float)v3[c]);
  }
  for (; j < b; j++) {
    f16x8 va = t0[(size_t)csr[j] * 16 + l];
#pragma unroll
    for (int c = 0; c < 8; c++) s0[c] += (float)va[c];
  }
  a = valid ? off[N + nd] : 0; b = valid ? off[N + nd + 1] : 0;
  j = a;
  for (; j + 3 < b; j += 4) {
    int i0 = csr[j], i1 = csr[j + 1], i2 = csr[j + 2], i3 = csr[j + 3];
    f16x8 v0 = t1[(size_t)i0 * 16 + l];
    f16x8 v1 = t1[(size_t)i1 * 16 + l];
    f16x8 v2 = t1[(size_t)i2 * 16 + l];
    f16x8 v3 = t1[(size_t)i3 * 16 + l];
#pragma unroll
    for (int c = 0; c < 8; c++)
      s1[c] += ((float)v0[c] + (float)v1[c]) + ((float)v2[c] + (float)v3[c]);
  }
  for (; j < b; j++) {
    f16x8 va = t1[(size_t)csr[j] * 16 + l];
#pragma unroll
    for (int c = 0; c < 8; c++) s1[c] += (float)va[c];
  }
  float o[8] = {0,0,0,0,0,0,0,0};
  if (valid) {
    float d0 = dinv[nd], d1 = dinv[N + nd];
    const float4* B0 = (const float4*)(b0 + l * 8);
    const float4* B1 = (const float4*)(b1 + l * 8);
    float4 ba0 = B0[0], ba1 = B0[1], bb0 = B1[0], bb1 = B1[1];
    float bs[8] = {ba0.x + bb0.x, ba0.y + bb0.y, ba0.z + bb0.z, ba0.w + bb0.w,
                   ba1.x + bb1.x, ba1.y + bb1.y, ba1.z + bb1.z, ba1.w + bb1.w};
#pragma unroll
    for (int c = 0; c < 8; c++) o[c] = d0 * s0[c] + d1 * s1[c] + bs[c];
    float* dst = outh + (size_t)nd * 128 + l * 8;
    *(float4*)dst = make_float4(o[0], o[1], o[2], o[3]);
    *(float4*)(dst + 4) = make_float4(o[4], o[5], o[6], o[7]);
  }
  float sv[8], q[8];
#pragma unroll
  for (int c = 0; c < 8; c++) { sv[c] = o[c]; q[c] = o[c] * o[c]; }
#pragma unroll
  for (int c = 0; c < 8; c++) {
    sv[c] += __shfl_xor(sv[c], 16); sv[c] += __shfl_xor(sv[c], 32);
    q[c] += __shfl_xor(q[c], 16);  q[c] += __shfl_xor(q[c], 32);
  }
  int lane = t & 63, wid = t >> 6;
  if (lane < 16) {
#pragma unroll
    for (int c = 0; c < 8; c++) { reds[wid][lane * 8 + c] = sv[c]; redq[wid][lane * 8 + c] = q[c]; }
  }
  __syncthreads();
  if (t < 128) {
    float ts = reds[0][t] + reds[1][t] + reds[2][t] + reds[3][t];
    float tq = redq[0][t] + redq[1][t] + redq[2][t] + redq[3][t];
    int cp = blockIdx.x & 7;
    atomicAdd(&stats[cp * 128 + t], ts);
    atomicAdd(&stats[1024 + cp * 128 + t], tq);
  }
}

// ---------------- per-head fused chain: e->t->p, 64 nodes, 128 threads (2 waves) ----
#define TPH 136
__global__ __launch_bounds__(128) void heads_kernel(
    const unsigned short* __restrict__ Wp,
    const float* __restrict__ h, const float* __restrict__ stats,
    const float* __restrict__ g2, const float* __restrict__ bt2,
    const float* __restrict__ emb1_b, const float* __restrict__ emb2_b,
    const float* __restrict__ ph1_ba, const float* __restrict__ ph1_bb,
    const float* __restrict__ ph2_ba, const float* __restrict__ ph2_bb,
    float* __restrict__ out, int n, float invn) {
  __shared__ float bnsc[128], bnsh[128];
  __shared__ _Float16 tile[64 * TPH];
  __shared__ float l2red[4][16][2];
  const int t = threadIdx.x;
  {
    float s = 0.f, q = 0.f;
#pragma unroll
    for (int r = 0; r < 8; r++) { s += stats[r * 128 + t]; q += stats[1024 + r * 128 + t]; }
    float mu = s * invn, var = q * invn - mu * mu;
    float sc = g2[t] * rsqrtf(var + 1e-5f);
    bnsc[t] = sc; bnsh[t] = bt2[t] - mu * sc;
  }
  __syncthreads();

  const int lane = t & 63;
  const int wj = t >> 6;                 // feature half (2 waves)
  const int wh = blockIdx.x & 1;         // head
  const int base = ((int)blockIdx.x >> 1) * 64;
  const int lrow = lane & 15, lgrp = lane >> 4;
  const int jtbase = wj * 4;
  const size_t ND = (size_t)n * 128;

  int node[4];
  bool valid[4];
#pragma unroll
  for (int it = 0; it < 4; it++) {
    int i = base + it * 16 + lrow;
    valid[it] = (i < n);
    node[it] = valid[it] ? i : (n - 1);
  }

  f32x4 acc[4][4];
  const unsigned short* slot;
  const float* bias;

  // stage 1: e = tanh(BN(h) @ W[6+wh] + emb_b)  (bf16 split, exact)
  slot = Wp + (size_t)(6 + wh) * 32768;
  bias = wh ? emb2_b : emb1_b;
#pragma unroll
  for (int jt = 0; jt < 4; jt++) {
    float4 b4 = *(const float4*)(bias + (jtbase + jt) * 16 + lgrp * 4);
#pragma unroll
    for (int it = 0; it < 4; it++) acc[jt][it] = (f32x4){b4.x, b4.y, b4.z, b4.w};
  }
#pragma unroll
  for (int ks = 0; ks < 4; ks++) {
    int cb = ks * 32 + lgrp * 8;
    float sck[8], shk[8];
#pragma unroll
    for (int c = 0; c < 8; c++) { sck[c] = bnsc[cb + c]; shk[c] = bnsh[cb + c]; }
    bf16x8 awh[4], awl[4];
#pragma unroll
    for (int jt = 0; jt < 4; jt++) {
      size_t fo = (size_t)(((jtbase + jt) * 4 + ks) * 64 + lane) * 8;
      awh[jt] = *(const bf16x8*)(slot + fo);
      awl[jt] = *(const bf16x8*)(slot + fo + 16384);
    }
#pragma unroll
    for (int it = 0; it < 4; it++) {
      const float* src = h + (size_t)node[it] * 128 + cb;
      float4 u0 = *(const float4*)src;
      float4 u1 = *(const float4*)(src + 4);
      float vv[8] = {u0.x, u0.y, u0.z, u0.w, u1.x, u1.y, u1.z, u1.w};
#pragma unroll
      for (int c = 0; c < 8; c++) vv[c] = vv[c] * sck[c] + shk[c];
      bf16x8 bhh, bhl;
      split8(vv, bhh, bhl);
#pragma unroll
      for (int jt = 0; jt < 4; jt++) {
        acc[jt][it] = __builtin_amdgcn_mfma_f32_16x16x32_bf16(awh[jt], bhh, acc[jt][it], 0, 0, 0);
        acc[jt][it] = __builtin_amdgcn_mfma_f32_16x16x32_bf16(awl[jt], bhh, acc[jt][it], 0, 0, 0);
        acc[jt][it] = __builtin_amdgcn_mfma_f32_16x16x32_bf16(awh[jt], bhl, acc[jt][it], 0, 0, 0);
      }
    }
  }
#pragma unroll
  for (int jt = 0; jt < 4; jt++)
#pragma unroll
    for (int it = 0; it < 4; it++)
#pragma unroll
      for (int c = 0; c < 4; c++) acc[jt][it][c] = fast_tanh(acc[jt][it][c]);

  float rsv[4];
  if (wh == 1) {  // e2 l2norm (cross-wave reduce)
#pragma unroll
    for (int it = 0; it < 4; it++) {
      float rs = 0.f;
#pragma unroll
      for (int jt = 0; jt < 4; jt++)
#pragma unroll
        for (int c = 0; c < 4; c++) rs += acc[jt][it][c] * acc[jt][it][c];
      rs += __shfl_xor(rs, 16);
      rs += __shfl_xor(rs, 32);
      rsv[it] = rs;
      if (lane < 16) l2red[it][lane][wj] = rs;
    }
    __syncthreads();
#pragma unroll
    for (int it = 0; it < 4; it++) {
      float full = rsv[it] + l2red[it][lrow][wj ^ 1];
      float scl = 1.f / fmaxf(sqrtf(full), 1e-12f);
#pragma unroll
      for (int jt = 0; jt < 4; jt++)
#pragma unroll
        for (int c = 0; c < 4; c++) acc[jt][it][c] *= scl;
    }
  }
#pragma unroll
  for (int it = 0; it < 4; it++) {
#pragma unroll
    for (int jt = 0; jt < 4; jt++) {
      if (valid[it])
        *(float4*)(out + (size_t)wh * ND + (size_t)node[it] * 128 + (jtbase + jt) * 16 + lgrp * 4) =
            make_float4(acc[jt][it][0], acc[jt][it][1], acc[jt][it][2], acc[jt][it][3]);
      _Float16 o4[4];
#pragma unroll
      for (int c = 0; c < 4; c++) o4[c] = (_Float16)acc[jt][it][c];
      *(uint2*)(tile + (it * 16 + lrow) * TPH + (jtbase + jt) * 16 + lgrp * 4) = *(uint2*)o4;
    }
  }
  __syncthreads();

  // stage 2: t = relu(e @ W[8+2wh] + ph_ba)  (f16 hi/lo)
  slot = Wp + (size_t)(8 + 2 * wh) * 32768;
  bias = wh ? ph2_ba : ph1_ba;
#pragma unroll
  for (int jt = 0; jt < 4; jt++) {
    float4 b4 = *(const float4*)(bias + (jtbase + jt) * 16 + lgrp * 4);
#pragma unroll
    for (int it = 0; it < 4; it++) acc[jt][it] = (f32x4){b4.x, b4.y, b4.z, b4.w};
  }
#pragma unroll
  for (int ks = 0; ks < 4; ks++) {
    f16x8 awh[4], awl[4];
#pragma unroll
    for (int jt = 0; jt < 4; jt++) {
      size_t fo = (size_t)(((jtbase + jt) * 4 + ks) * 64 + lane) * 8;
      awh[jt] = *(const f16x8*)(slot + fo);
      awl[jt] = *(const f16x8*)(slot + fo + 16384);
    }
#pragma unroll
    for (int it = 0; it < 4; it++) {
      f16x8 bh = *(const f16x8*)(tile + (it * 16 + lrow) * TPH + ks * 32 + lgrp * 8);
#pragma unroll
      for (int jt = 0; jt < 4; jt++) {
        acc[jt][it] = __builtin_amdgcn_mfma_f32_16x16x32_f16(awh[jt], bh, acc[jt][it], 0, 0, 0);
        acc[jt][it] = __builtin_amdgcn_mfma_f32_16x16x32_f16(awl[jt], bh, acc[jt][it], 0, 0, 0);
      }
    }
  }
#pragma unroll
  for (int jt = 0; jt < 4; jt++)
#pragma unroll
    for (int it = 0; it < 4; it++)
#pragma unroll
      for (int c = 0; c < 4; c++) acc[jt][it][c] = fmaxf(acc[jt][it][c], 0.f);
  __syncthreads();
#pragma unroll
  for (int it = 0; it < 4; it++)
#pragma unroll
    for (int jt = 0; jt < 4; jt++) {
      _Float16 o4[4];
#pragma unroll
      for (int c = 0; c < 4; c++) o4[c] = (_Float16)acc[jt][it][c];
      *(uint2*)(tile + (it * 16 + lrow) * TPH + (jtbase + jt) * 16 + lgrp * 4) = *(uint2*)o4;
    }
  __syncthreads();

  // stage 3: p = l2norm(t @ W[9+2wh] + ph_bb)  (f16 hi/lo)
  slot = Wp + (size_t)(9 + 2 * wh) * 32768;
  bias = wh ? ph2_bb : ph1_bb;
#pragma unroll
  for (int jt = 0; jt < 4; jt++) {
    float4 b4 = *(const float4*)(bias + (jtbase + jt) * 16 + lgrp * 4);
#pragma unroll
    for (int it = 0; it < 4; it++) acc[jt][it] = (f32x4){b4.x, b4.y, b4.z, b4.w};
  }
#pragma unroll
  for (int ks = 0; ks < 4; ks++) {
    f16x8 awh[4], awl[4];
#pragma unroll
    for (int jt = 0; jt < 4; jt++) {
      size_t fo = (size_t)(((jtbase + jt) * 4 + ks) * 64 + lane) * 8;
      awh[jt] = *(const f16x8*)(slot + fo);
      awl[jt] = *(const f16x8*)(slot + fo + 16384);
    }
#pragma unroll
    for (int it = 0; it < 4; it++) {
      f16x8 bh = *(const f16x8*)(tile + (it * 16 + lrow) * TPH + ks * 32 + lgrp * 8);
#pragma unroll
      for (int jt = 0; jt < 4; jt++) {
        acc[jt][it] = __builtin_amdgcn_mfma_f32_16x16x32_f16(awh[jt], bh, acc[jt][it], 0, 0, 0);
        acc[jt][it] = __builtin_amdgcn_mfma_f32_16x16x32_f16(awl[jt], bh, acc[jt][it], 0, 0, 0);
      }
    }
  }
#pragma unroll
  for (int it = 0; it < 4; it++) {
    float rs = 0.f;
#pragma unroll
    for (int jt = 0; jt < 4; jt++)
#pragma unroll
      for (int c = 0; c < 4; c++) rs += acc[jt][it][c] * acc[jt][it][c];
    rs += __shfl_xor(rs, 16);
    rs += __shfl_xor(rs, 32);
    rsv[it] = rs;
    if (lane < 16) l2red[it][lane][wj] = rs;
  }
  __syncthreads();
#pragma unroll
  for (int it = 0; it < 4; it++) {
    float full = rsv[it] + l2red[it][lrow][wj ^ 1];
    float scl = 1.f / fmaxf(sqrtf(full), 1e-12f);
    if (!valid[it]) continue;
#pragma unroll
    for (int jt = 0; jt < 4; jt++)
      *(float4*)(out + (size_t)(2 + wh) * ND + (size_t)node[it] * 128 + (jtbase + jt) * 16 + lgrp * 4) =
          make_float4(acc[jt][it][0] * scl, acc[jt][it][1] * scl,
                      acc[jt][it][2] * scl, acc[jt][it][3] * scl);
  }
}

// ---------------- launch ----------------
extern "C" void kernel_launch(void* const* d_in, const int* in_sizes, int n_in,
                              void* d_out, int out_size, void* d_ws, size_t ws_size,
                              hipStream_t stream) {
  const float* x      = (const float*)d_in[0];
  const int*   ei0    = (const int*)d_in[1];
  const int*   ei1    = (const int*)d_in[2];
  const float* W0     = (const float*)d_in[3];
  const float* b0     = (const float*)d_in[4];
  const float* W1     = (const float*)d_in[5];
  const float* b1     = (const float*)d_in[6];
  const float* gamma  = (const float*)d_in[7];
  const float* beta   = (const float*)d_in[8];
  const float* emb1_W = (const float*)d_in[9];
  const float* emb1_b = (const float*)d_in[10];
  const float* emb2_W = (const float*)d_in[11];
  const float* emb2_b = (const float*)d_in[12];
  const float* ph1_Wa = (const float*)d_in[13];
  const float* ph1_ba = (const float*)d_in[14];
  const float* ph1_Wb = (const float*)d_in[15];
  const float* ph1_bb = (const float*)d_in[16];
  const float* ph2_Wa = (const float*)d_in[17];
  const float* ph2_ba = (const float*)d_in[18];
  const float* ph2_Wb = (const float*)d_in[19];
  const float* ph2_bb = (const float*)d_in[20];

  const int N = in_sizes[0] / D;
  const int E = in_sizes[1] / 2;
  const int N2 = 2 * N;
  const size_t ND = (size_t)N * D;
  const float invn = 1.0f / (float)N;
  float* out = (float*)d_out;

  char* p = (char*)d_ws;
  auto carve = [&](size_t bytes) -> void* {
    void* r = (void*)p;
    p += (bytes + 255) & ~(size_t)255;
    return r;
  };
  int*   cnt   = (int*)carve((size_t)N2 * 4);
  float* stats = (float*)carve((size_t)3 * 2048 * 4);   // [layer][2][8][128]
  size_t zbytes = (size_t)((char*)(stats + 3 * 2048) - (char*)cnt);
  int*   off   = (int*)carve((size_t)(N2 + 1) * 4);
  float* dinv  = (float*)carve((size_t)N2 * 4);
  int*   csr   = (int*)carve((size_t)2 * E * 4);
  int*   rank0 = (int*)carve((size_t)E * 4);
  int*   rank1 = (int*)carve((size_t)E * 4);
  int*   bsum  = (int*)carve(256 * 4);
  unsigned short* Wp = (unsigned short*)carve((size_t)12 * 32768 * 2);
  float* hbuf = (float*)carve(4 * ND);
  _Float16* tab0 = (_Float16*)carve(2 * ND);
  _Float16* tab1 = (_Float16*)carve(2 * ND);

  const int TPB = 256;
  const int packBlocks = 768;
  const int gridPC = packBlocks + (E + TPB - 1) / TPB;
  const int fillBlocks = (E + TPB - 1) / TPB;
  const int nbScan = (N2 + 511) / 512;
  const int gridDual = (N + 63) / 64;
  const int gridGath = (N + 15) / 16;
  const int gridHd = 2 * ((N + 63) / 64);

  WPtrs P;
  P.w[0] = W0;                     P.w[1] = W1;
  P.w[2] = W0 + (size_t)D * D;     P.w[3] = W1 + (size_t)D * D;
  P.w[4] = W0 + (size_t)2 * D * D; P.w[5] = W1 + (size_t)2 * D * D;
  P.w[6] = emb1_W; P.w[7] = emb2_W;
  P.w[8] = ph1_Wa; P.w[9] = ph1_Wb;
  P.w[10] = ph2_Wa; P.w[11] = ph2_Wb;

  hipMemsetAsync(cnt, 0, zbytes, stream);
  packcount_kernel<<<gridPC, TPB, 0, stream>>>(P, Wp, ei0 + E, ei1 + E, cnt,
                                               rank0, rank1, E, N, packBlocks);
  scan_part_kernel<<<nbScan, TPB, 0, stream>>>(cnt, off, bsum, N2);
  scan_addm_kernel<<<nbScan, TPB, 0, stream>>>(off, bsum, cnt, dinv, N2, nbScan);

  fillmm0_kernel<<<fillBlocks + gridDual, TPB, 0, stream>>>(
      ei0, ei1, off, rank0, rank1, csr, E, fillBlocks, Wp, x, dinv, tab0, tab1, N, N);
  gather_kernel<<<gridGath, TPB, 0, stream>>>(tab0, tab1, dinv, off, csr,
                                              b0, b1, hbuf, stats, N, N);
  for (int i = 1; i < 3; i++) {
    mm_dual_k<<<gridDual, TPB, 0, stream>>>(Wp + (size_t)(2 * i) * 32768, hbuf,
                                            stats + (size_t)(i - 1) * 2048,
                                            gamma + (i - 1) * D, beta + (i - 1) * D,
                                            dinv, tab0, tab1, N, N, invn);
    gather_kernel<<<gridGath, TPB, 0, stream>>>(tab0, tab1, dinv, off, csr,
                                                b0 + i * D, b1 + i * D, hbuf,
                                                stats + (size_t)i * 2048, N, N);
  }
  heads_kernel<<<gridHd, 128, 0, stream>>>(
      Wp, hbuf, stats + (size_t)2 * 2048, gamma + 2 * D, beta + 2 * D,
      emb1_b, emb2_b, ph1_ba, ph1_bb, ph2_ba, ph2_bb, out, N, invn);
}